// Round 2
// baseline (1020.613 us; speedup 1.0000x reference)
//
#include <hip/hip_runtime.h>
#include <hip/hip_bf16.h>
#include <stdint.h>

typedef __bf16 bf16;
typedef __bf16 bf16x8 __attribute__((ext_vector_type(8)));
typedef __bf16 bf16x4 __attribute__((ext_vector_type(4)));
typedef float  f32x4  __attribute__((ext_vector_type(4)));

#define LDS_PTR(p) ((__attribute__((address_space(3))) uint32_t*)(p))
#define GLB_PTR(p) ((const __attribute__((address_space(1))) uint32_t*)(p))

static constexpr int BATCH = 4, SEQ = 4096, DMODEL = 1024;
static constexpr int DI = 2048;
static constexpr int MTOK = BATCH * SEQ;   // 16384 tokens

enum { EPI_SPLIT = 0, EPI_PLAIN = 1, EPI_GATEADD = 2, EPI_RES = 3 };

// ---------------------------------------------------------------------------
// 128x128-tile bf16 GEMM (m97 structure) — kept for the small prep GEMMs
// and the skinny split-K P GEMM.
// ---------------------------------------------------------------------------
template <int EPI, bool SPLITK = false>
__global__ __launch_bounds__(256) void gemm_bt(
    const bf16* __restrict__ Aact, const bf16* __restrict__ W,
    const float* __restrict__ bias,
    bf16* __restrict__ out0, bf16* __restrict__ out1,
    const bf16* __restrict__ gate,
    float* __restrict__ outf, const float* __restrict__ resid,
    int N, int K, int ldC, int col_off)
{
  __shared__ __align__(16) bf16 sA[128 * 64];
  __shared__ __align__(16) bf16 sB[128 * 64];
  const int tid  = threadIdx.x;
  int n0, m0, kbeg, kend;
  size_t out_off = 0;
  if (SPLITK) {
    n0 = 0; m0 = blockIdx.y * 128;
    const int kh = K / gridDim.x;
    kbeg = blockIdx.x * kh; kend = kbeg + kh;
    out_off = (size_t)blockIdx.x * ((size_t)MTOK * 128);
  } else {
    const int nT  = gridDim.x;
    const int lin = blockIdx.y * nT + blockIdx.x;
    const int grp = lin / (8 * nT);
    const int within = lin - grp * (8 * nT);
    n0 = (within >> 3) * 128;
    m0 = (grp * 8 + (within & 7)) * 128;
    kbeg = 0; kend = K;
  }
  const int lane = tid & 63;
  const int wv   = tid >> 6;
  const int wr   = wv >> 1, wc = wv & 1;
  const int l15  = lane & 15, quad = lane >> 4;

  f32x4 acc[4][4];
#pragma unroll
  for (int i = 0; i < 4; ++i)
#pragma unroll
    for (int j = 0; j < 4; ++j) acc[i][j] = (f32x4){0.f, 0.f, 0.f, 0.f};

  int rr[4], cb[4];
#pragma unroll
  for (int j = 0; j < 4; ++j) {
    const int s = tid + j * 256;
    rr[j] = s >> 3;
    cb[j] = ((s & 7) ^ (rr[j] & 7)) * 16;
  }

  const char* gA = (const char*)(Aact + (size_t)m0 * K);
  const char* gW = (const char*)(W + (size_t)n0 * K);

  for (int k0 = kbeg; k0 < kend; k0 += 64) {
    if (k0 != kbeg) __syncthreads();
#pragma unroll
    for (int j = 0; j < 4; ++j)
      __builtin_amdgcn_global_load_lds(GLB_PTR(gA + ((size_t)rr[j] * K + k0) * 2 + cb[j]),
                                       LDS_PTR(sA + (tid + j * 256) * 8), 16, 0, 0);
#pragma unroll
    for (int j = 0; j < 4; ++j)
      __builtin_amdgcn_global_load_lds(GLB_PTR(gW + ((size_t)rr[j] * K + k0) * 2 + cb[j]),
                                       LDS_PTR(sB + (tid + j * 256) * 8), 16, 0, 0);
    __syncthreads();

#pragma unroll
    for (int h = 0; h < 2; ++h) {
      bf16x8 av[4], bv[4];
#pragma unroll
      for (int t = 0; t < 4; ++t) {
        const int Ra = wr * 64 + t * 16 + l15;
        const int Rb = wc * 64 + t * 16 + l15;
        const int cc = h * 4 + quad;
        av[t] = *(const bf16x8*)(sA + (Ra * 8 + (cc ^ (Ra & 7))) * 8);
        bv[t] = *(const bf16x8*)(sB + (Rb * 8 + (cc ^ (Rb & 7))) * 8);
      }
#pragma unroll
      for (int i = 0; i < 4; ++i)
#pragma unroll
        for (int j = 0; j < 4; ++j)
          acc[i][j] = __builtin_amdgcn_mfma_f32_16x16x32_bf16(av[i], bv[j], acc[i][j], 0, 0, 0);
    }
  }

  bf16* o0 = out0 + out_off;
#pragma unroll
  for (int i = 0; i < 4; ++i) {
    const int mbase = m0 + wr * 64 + i * 16 + quad * 4;
#pragma unroll
    for (int j = 0; j < 4; ++j) {
      const int n = n0 + wc * 64 + j * 16 + l15;
      const float bj = bias ? bias[n] : 0.f;
#pragma unroll
      for (int r = 0; r < 4; ++r) {
        const int mm = mbase + r;
        float v = acc[i][j][r] + bj;
        if (EPI == EPI_SPLIT) {
          if (n < DI) o0[(size_t)mm * DI + n] = (bf16)(1.f / (1.f + __expf(-v)));
          else        out1[(size_t)mm * DI + (n - DI)] = (bf16)v;
        } else if (EPI == EPI_PLAIN) {
          o0[(size_t)mm * ldC + col_off + n] = (bf16)v;
        } else if (EPI == EPI_GATEADD) {
          const size_t idx = (size_t)mm * ldC + n;
          float zz = (float)o0[idx];
          float g  = (float)gate[(size_t)mm * DI + n];
          o0[idx] = (bf16)((v + zz) * g);
        } else {
          outf[(size_t)mm * ldC + n] = v + resid[(size_t)mm * ldC + n];
        }
      }
    }
  }
}

// ---------------------------------------------------------------------------
// 256x256-tile, 8-wave, 8-phase bf16 GEMM (m201 structure):
//   BK=64, double-buffered 128 KiB LDS (selected by integer offset cur/nxt),
//   counted vmcnt (never 0 in main loop), setprio(1) around each 16-MFMA
//   cluster, one half-tile (2 global_load_lds) staged per phase.
// Phase (QR,QC) computes one 128x128 C-quadrant over the full K=64 tile and
// reads only A-half QR and B-half QC. vmcnt deadline audit (per-wave queue,
// oldest first, 2 loads per stage):
//   main phase wait point: outstanding = {prev-tile h1 x2, this-tile issued}
//   = 6 -> vmcnt(4) retires exactly the half-tile the NEXT phase reads;
//   the phase's first s_barrier publishes it cross-wave. Epilogue 4->2->0.
// LDS swizzle identical to gemm_bt (measured 0 conflicts): within a half,
// row r slot sc holds global chunk cc = sc ^ (r&7); global source is
// pre-swizzled so global_load_lds's linear wave dest is respected.
// ---------------------------------------------------------------------------
template <int N> __device__ __forceinline__ void vmwait() {
  if constexpr (N == 0)      asm volatile("s_waitcnt vmcnt(0)" ::: "memory");
  else if constexpr (N == 2) asm volatile("s_waitcnt vmcnt(2)" ::: "memory");
  else if constexpr (N == 4) asm volatile("s_waitcnt vmcnt(4)" ::: "memory");
}

#define G256_STAGE(gmat, smat, dstoff, half, k0)                                  \
  do {                                                                            \
    const char* _g = (gmat) + ((size_t)((half) * 128 + r0) * K + (size_t)(k0)) * 2 + c0; \
    const int _d = (dstoff) + (half) * 8192 + tid * 8;                            \
    __builtin_amdgcn_global_load_lds(GLB_PTR(_g), LDS_PTR((smat) + _d), 16, 0, 0); \
    __builtin_amdgcn_global_load_lds(GLB_PTR(_g + (size_t)128 * K),               \
                                     LDS_PTR((smat) + _d + 4096), 16, 0, 0);      \
  } while (0)

// STM: 0 = stage A-half STH, 1 = stage B-half STH, 2 = no stage (epilogue)
#define G256_PHASE(QR, QC, STM, STH, VM)                                          \
  do {                                                                            \
    bf16x8 av[2][4], bv[2][2];                                                    \
    _Pragma("unroll")                                                             \
    for (int kk = 0; kk < 2; ++kk) {                                              \
      const int cc = kk * 4 + quad;                                               \
      _Pragma("unroll")                                                           \
      for (int i = 0; i < 4; ++i) {                                               \
        const int R = (QR) * 128 + wr * 64 + i * 16 + l15;                        \
        av[kk][i] = *(const bf16x8*)(sA + cur + (R >> 7) * 8192 +                 \
                                     ((R & 127) * 8 + (cc ^ (R & 7))) * 8);       \
      }                                                                           \
      _Pragma("unroll")                                                           \
      for (int j = 0; j < 2; ++j) {                                               \
        const int R = (QC) * 128 + wc * 32 + j * 16 + l15;                        \
        bv[kk][j] = *(const bf16x8*)(sB + cur + (R >> 7) * 8192 +                 \
                                     ((R & 127) * 8 + (cc ^ (R & 7))) * 8);       \
      }                                                                           \
    }                                                                             \
    if ((STM) == 0)      G256_STAGE(gA, sA, nxt, (STH), knext);                   \
    else if ((STM) == 1) G256_STAGE(gW, sB, nxt, (STH), knext);                   \
    vmwait<VM>();                                                                 \
    __builtin_amdgcn_s_barrier();                                                 \
    asm volatile("s_waitcnt lgkmcnt(0)" ::: "memory");                            \
    __builtin_amdgcn_sched_barrier(0);                                            \
    __builtin_amdgcn_s_setprio(1);                                                \
    _Pragma("unroll")                                                             \
    for (int kk = 0; kk < 2; ++kk)                                                \
      _Pragma("unroll")                                                           \
      for (int i = 0; i < 4; ++i)                                                 \
        _Pragma("unroll")                                                         \
        for (int j = 0; j < 2; ++j)                                               \
          acc[QR][QC][i][j] = __builtin_amdgcn_mfma_f32_16x16x32_bf16(            \
              av[kk][i], bv[kk][j], acc[QR][QC][i][j], 0, 0, 0);                  \
    __builtin_amdgcn_s_setprio(0);                                                \
    __builtin_amdgcn_sched_barrier(0);                                            \
    __builtin_amdgcn_s_barrier();                                                 \
    __builtin_amdgcn_sched_barrier(0);                                            \
  } while (0)

template <int EPI>
__global__ __launch_bounds__(512, 2) void gemm256(
    const bf16* __restrict__ Aact, const bf16* __restrict__ W,
    const float* __restrict__ bias,
    bf16* __restrict__ out0, bf16* __restrict__ out1,
    const bf16* __restrict__ gate,
    float* __restrict__ outf, const float* __restrict__ resid,
    int K, int ldC)
{
  __shared__ __align__(16) bf16 sA[2 * 16384];   // 2 buf x 256 rows x 64 k
  __shared__ __align__(16) bf16 sB[2 * 16384];
  const int tid = threadIdx.x;

  // GM=8 m-group swizzle: each XCD sweeps n at a fixed m-group (L2 locality)
  const int nT  = gridDim.x;
  const int lin = blockIdx.y * nT + blockIdx.x;
  const int grp = lin / (8 * nT);
  const int within = lin - grp * (8 * nT);
  const int n0 = (within >> 3) * 256;
  const int m0 = (grp * 8 + (within & 7)) * 256;

  const int lane = tid & 63;
  const int wv   = tid >> 6;        // 0..7
  const int wr   = wv >> 2;         // 0..1 : 64-row slice within quadrant
  const int wc   = wv & 3;          // 0..3 : 32-col slice within quadrant
  const int l15  = lane & 15, quad = lane >> 4;

  f32x4 acc[2][2][4][2];
#pragma unroll
  for (int a = 0; a < 2; ++a)
#pragma unroll
    for (int b = 0; b < 2; ++b)
#pragma unroll
      for (int i = 0; i < 4; ++i)
#pragma unroll
        for (int j = 0; j < 2; ++j) acc[a][b][i][j] = (f32x4){0.f, 0.f, 0.f, 0.f};

  // staging geometry: 1024 chunks per half-tile, 2 per thread (rows r0, r0+64)
  const int r0 = tid >> 3;
  const int c0 = ((tid & 7) ^ (r0 & 7)) * 16;   // same for r0+64: (r0+64)&7 == r0&7

  const char* gA = (const char*)(Aact + (size_t)m0 * K);
  const char* gW = (const char*)(W + (size_t)n0 * K);

  const int NT = K >> 6;

  // prologue: stage tile 0 fully into buffer 0, single drain
  G256_STAGE(gA, sA, 0, 0, 0);
  G256_STAGE(gA, sA, 0, 1, 0);
  G256_STAGE(gW, sB, 0, 0, 0);
  G256_STAGE(gW, sB, 0, 1, 0);
  asm volatile("s_waitcnt vmcnt(0)" ::: "memory");
  __builtin_amdgcn_s_barrier();

  int cur = 0;
  for (int t = 0; t < NT - 1; ++t) {
    const int knext = (t + 1) * 64;
    const int nxt = cur ^ 16384;
    G256_PHASE(0, 0, 0, 0, 4);   // compute q(0,0), stage next A.h0
    G256_PHASE(1, 0, 1, 0, 4);   // compute q(1,0), stage next B.h0
    G256_PHASE(0, 1, 0, 1, 4);   // compute q(0,1), stage next A.h1
    G256_PHASE(1, 1, 1, 1, 4);   // compute q(1,1), stage next B.h1
    cur = nxt;
  }
  {
    // epilogue tile: no stages, drain 4 -> 2 -> 0
    const int knext = 0;
    const int nxt = cur;
    (void)knext; (void)nxt;
    G256_PHASE(0, 0, 2, 0, 2);
    G256_PHASE(1, 0, 2, 0, 0);
    G256_PHASE(0, 1, 2, 0, -1);
    G256_PHASE(1, 1, 2, 0, -1);
  }

  // epilogue write: C/D layout col = lane&15, row = quad*4 + r (m89-verified)
#pragma unroll
  for (int qr = 0; qr < 2; ++qr)
#pragma unroll
    for (int qc = 0; qc < 2; ++qc)
#pragma unroll
      for (int i = 0; i < 4; ++i) {
        const int mbase = m0 + qr * 128 + wr * 64 + i * 16 + quad * 4;
#pragma unroll
        for (int j = 0; j < 2; ++j) {
          const int n = n0 + qc * 128 + wc * 32 + j * 16 + l15;
          const float bj = bias ? bias[n] : 0.f;
#pragma unroll
          for (int r = 0; r < 4; ++r) {
            const int mm = mbase + r;
            float v = acc[qr][qc][i][j][r] + bj;
            if (EPI == EPI_SPLIT) {
              if (n < DI) out0[(size_t)mm * DI + n] = (bf16)(1.f / (1.f + __expf(-v)));
              else        out1[(size_t)mm * DI + (n - DI)] = (bf16)v;
            } else if (EPI == EPI_GATEADD) {
              const size_t idx = (size_t)mm * ldC + n;
              float zz = (float)out0[idx];
              float g  = (float)gate[(size_t)mm * DI + n];
              out0[idx] = (bf16)((v + zz) * g);
            } else {  // EPI_RES
              outf[(size_t)mm * ldC + n] = v + resid[(size_t)mm * ldC + n];
            }
          }
        }
      }
}

// ---------------------------------------------------------------------------
// RMSNorm: one block per token row (1024 fp32 -> 1024 bf16)
// ---------------------------------------------------------------------------
__global__ __launch_bounds__(256) void rmsnorm_kernel(
    const float* __restrict__ x, const float* __restrict__ w, bf16* __restrict__ out)
{
  const int row = blockIdx.x;
  const int tid = threadIdx.x;
  const float4 xv = ((const float4*)(x + (size_t)row * DMODEL))[tid];
  float s = xv.x * xv.x + xv.y * xv.y + xv.z * xv.z + xv.w * xv.w;
#pragma unroll
  for (int o = 32; o; o >>= 1) s += __shfl_xor(s, o);
  __shared__ float red[4];
  if ((tid & 63) == 0) red[tid >> 6] = s;
  __syncthreads();
  const float tot = red[0] + red[1] + red[2] + red[3];
  const float scale = rsqrtf(tot * (1.f / DMODEL) + 1e-6f);
  const float4 wv = ((const float4*)w)[tid];
  bf16x4 o4 = { (bf16)(xv.x * wv.x * scale), (bf16)(xv.y * wv.y * scale),
                (bf16)(xv.z * wv.z * scale), (bf16)(xv.w * wv.w * scale) };
  *(bf16x4*)(out + (size_t)row * DMODEL + tid * 4) = o4;
}

// ---------------------------------------------------------------------------
// 9-tap depthwise conv + silu, 4 channels/thread (bf16x4 loads).
// ---------------------------------------------------------------------------
static constexpr int TL2 = 64;
__global__ __launch_bounds__(256) void conv_kernel(
    const bf16* __restrict__ val,
    const float* __restrict__ sym_k, const float* __restrict__ sym_b,
    bf16* __restrict__ bbuf)
{
  const int d  = (blockIdx.y * 256 + threadIdx.x) * 4;
  const int b  = blockIdx.z;
  const int l0 = blockIdx.x * TL2;
  float wk[9][4], bs[4];
#pragma unroll
  for (int j = 0; j < 4; ++j) {
    bs[j] = sym_b[d + j];
#pragma unroll
    for (int k = 0; k < 9; ++k) wk[k][j] = sym_k[(d + j) * 9 + k];
  }
  const bf16* base = val + (size_t)b * SEQ * DI + d;

  float win[9][4];
#pragma unroll
  for (int j = 0; j < 8; ++j) {
    const int xr = l0 + j - 4;
    if (xr >= 0 && xr < SEQ) {
      bf16x4 v = *(const bf16x4*)(base + (size_t)xr * DI);
#pragma unroll
      for (int c = 0; c < 4; ++c) win[j][c] = (float)v[c];
    } else {
#pragma unroll
      for (int c = 0; c < 4; ++c) win[j][c] = 0.f;
    }
  }
  for (int t = 0; t < TL2; ++t) {
    const int xf = l0 + t + 4;
    if (xf < SEQ) {
      bf16x4 v = *(const bf16x4*)(base + (size_t)xf * DI);
#pragma unroll
      for (int c = 0; c < 4; ++c) win[8][c] = (float)v[c];
    } else {
#pragma unroll
      for (int c = 0; c < 4; ++c) win[8][c] = 0.f;
    }
    float sb[4];
#pragma unroll
    for (int c = 0; c < 4; ++c) sb[c] = bs[c];
#pragma unroll
    for (int k = 0; k < 9; ++k)
#pragma unroll
      for (int c = 0; c < 4; ++c) sb[c] += win[k][c] * wk[k][c];
    bf16x4 o;
#pragma unroll
    for (int c = 0; c < 4; ++c) o[c] = (bf16)(sb[c] / (1.f + __expf(-sb[c])));
    *(bf16x4*)(bbuf + ((size_t)b * SEQ + l0 + t) * DI + d) = o;
#pragma unroll
    for (int k = 0; k < 8; ++k)
#pragma unroll
      for (int c = 0; c < 4; ++c) win[k][c] = win[k + 1][c];
  }
}

// ---------------------------------------------------------------------------
// prep_cvt: merged fp32->bf16 conversions (in_w, hb_w, out_w)
// ---------------------------------------------------------------------------
__global__ __launch_bounds__(256) void prep_cvt_kernel(
    const float* __restrict__ in_w, const float* __restrict__ hb_w,
    const float* __restrict__ out_w,
    bf16* __restrict__ in_wbf, bf16* __restrict__ hb_bf, bf16* __restrict__ out_bf)
{
  const int b = blockIdx.x;
  const float* src; bf16* dst; size_t i;
  if (b < 4096)      { src = in_w;  dst = in_wbf; i = (size_t)b * 256 + threadIdx.x; }
  else if (b < 6144) { src = hb_w;  dst = hb_bf;  i = (size_t)(b - 4096) * 256 + threadIdx.x; }
  else               { src = out_w; dst = out_bf; i = (size_t)(b - 6144) * 256 + threadIdx.x; }
  const float4 v = ((const float4*)src)[i];
  bf16x4 o4 = { (bf16)v.x, (bf16)v.y, (bf16)v.z, (bf16)v.w };
  *(bf16x4*)(dst + 4 * i) = o4;
}

// pwT_bf[d][c] = (bf16)pw_w[c][d]   (2048x2048 transpose via LDS)
__global__ __launch_bounds__(256) void transpose_kernel(
    const float* __restrict__ in, bf16* __restrict__ out)
{
  __shared__ float s[32][33];
  const int tid = threadIdx.x;
  const int r = tid >> 5, x = tid & 31;
  const int c0 = blockIdx.y * 32, d0 = blockIdx.x * 32;
#pragma unroll
  for (int rr = r; rr < 32; rr += 8)
    s[rr][x] = in[(size_t)(c0 + rr) * 2048 + d0 + x];
  __syncthreads();
#pragma unroll
  for (int rr = r; rr < 32; rr += 8)
    out[(size_t)(d0 + rr) * 2048 + c0 + x] = (bf16)s[x][rr];
}

// ---------------------------------------------------------------------------
// prep_small: t1 (1024) | cvec (1) | bh (4) | wprep (8) | fbcopy (2048)
// ---------------------------------------------------------------------------
__global__ __launch_bounds__(256) void prep_small_kernel(
    const float* __restrict__ Bm, const float* __restrict__ ha_w,
    const float* __restrict__ dwa_b, const float* __restrict__ dwa_k,
    const float* __restrict__ A,
    const float* __restrict__ hb_w, const float* __restrict__ pw_b,
    const float* __restrict__ hb_b, const float* __restrict__ fuse_w,
    float* __restrict__ T1, float* __restrict__ cvec, float* __restrict__ b_H,
    bf16* __restrict__ Wp, bf16* __restrict__ Fb)
{
  const int b = blockIdx.x, tid = threadIdx.x;
  __shared__ float red[4][16];
  if (b < 1024) {
    const int o = b;
    float acc[16];
#pragma unroll
    for (int s = 0; s < 16; ++s) acc[s] = 0.f;
    for (int d = tid; d < 2048; d += 256) {
      const float w = ha_w[(size_t)o * 2048 + d];
#pragma unroll
      for (int s = 0; s < 16; ++s) acc[s] += Bm[s * 2048 + d] * w;
    }
    const int lane = tid & 63, wv = tid >> 6;
#pragma unroll
    for (int s = 0; s < 16; ++s) {
      float v = acc[s];
#pragma unroll
      for (int off = 32; off; off >>= 1) v += __shfl_xor(v, off);
      if (lane == s) red[wv][s] = v;
    }
    __syncthreads();
    if (tid < 16)
      T1[tid * 1024 + o] = red[0][tid] + red[1][tid] + red[2][tid] + red[3][tid];
  } else if (b == 1024) {
    float acc[16];
#pragma unroll
    for (int s = 0; s < 16; ++s) acc[s] = 0.f;
    for (int d = tid; d < 2048; d += 256) {
      const float w = dwa_b[d];
#pragma unroll
      for (int s = 0; s < 16; ++s) acc[s] += w * A[d * 16 + s];
    }
    const int lane = tid & 63, wv = tid >> 6;
#pragma unroll
    for (int s = 0; s < 16; ++s) {
      float v = acc[s];
#pragma unroll
      for (int off = 32; off; off >>= 1) v += __shfl_xor(v, off);
      if (lane == s) red[wv][s] = v;
    }
    __syncthreads();
    if (tid < 16) cvec[tid] = red[0][tid] + red[1][tid] + red[2][tid] + red[3][tid];
  } else if (b < 1029) {
    const int o = (b - 1025) * 256 + tid;
    float acc = hb_b[o];
    const float* hr = hb_w + (size_t)o * 2048;
    for (int c = 0; c < 2048; c += 4) {
      float4 h = *(const float4*)(hr + c);
      float4 p = *(const float4*)(pw_b + c);
      acc += h.x * p.x + h.y * p.y + h.z * p.z + h.w * p.w;
    }
    b_H[o] = acc;
  } else if (b < 1037) {
    const int d = (b - 1029) * 256 + tid;
    float kk[4], av[16];
#pragma unroll
    for (int k = 0; k < 4; ++k) kk[k] = dwa_k[d * 4 + k];
#pragma unroll
    for (int s = 0; s < 16; ++s) av[s] = A[d * 16 + s];
#pragma unroll
    for (int k = 0; k < 4; ++k)
#pragma unroll
      for (int s = 0; s < 16; ++s)
        Wp[(size_t)(k * 16 + s) * 2048 + d] = (bf16)(kk[k] * av[s]);
    for (int n = 64; n < 128; ++n) Wp[(size_t)n * 2048 + d] = (bf16)0.f;
  } else {
    const int idx = (b - 1037) * 256 + tid;
    const int n = idx >> 8, o4 = idx & 255;
    float4 v = ((const float4*)(fuse_w + (size_t)n * 2048 + 1024))[o4];
    bf16x4 o = { (bf16)v.x, (bf16)v.y, (bf16)v.z, (bf16)v.w };
    *(bf16x4*)(Fb + (size_t)n * 1024 + o4 * 4) = o;
  }
}

// ---------------------------------------------------------------------------
// prep_fuse: t2t (128 blocks) | biasz (8 blocks). Needs T1 and b_H.
// ---------------------------------------------------------------------------
__global__ __launch_bounds__(256) void prep_fuse_kernel(
    const float* __restrict__ T1, const float* __restrict__ fuse_w,
    const float* __restrict__ fuse_b, const float* __restrict__ ha_b,
    const float* __restrict__ b_H,
    float* __restrict__ T2t, float* __restrict__ bias_z)
{
  const int b = blockIdx.x, tid = threadIdx.x;
  if (b < 128) {
    const int n = b * 16 + (tid >> 4);
    const int s = tid & 15;
    const float* fr = fuse_w + (size_t)n * 2048;
    const float* tr = T1 + s * 1024;
    float acc = 0.f;
    for (int o = 0; o < 1024; o += 4) {
      float4 f = *(const float4*)(fr + o);
      float4 t = *(const float4*)(tr + o);
      acc += f.x * t.x + f.y * t.y + f.z * t.z + f.w * t.w;
    }
    T2t[n * 16 + s] = acc;
  } else {
    const int n = (b - 128) * 256 + tid;
    float acc = fuse_b[n];
    const float* fr = fuse_w + (size_t)n * 2048;
    for (int o = 0; o < 1024; o += 4) {
      float4 fa = *(const float4*)(fr + o);
      float4 fb = *(const float4*)(fr + 1024 + o);
      float4 ha = *(const float4*)(ha_b + o);
      float4 bh = *(const float4*)(b_H + o);
      acc += fa.x * ha.x + fa.y * ha.y + fa.z * ha.z + fa.w * ha.w;
      acc += fb.x * bh.x + fb.y * bh.y + fb.z * bh.z + fb.w * bh.w;
    }
    bias_z[n] = acc;
  }
}

// ---------------------------------------------------------------------------
// z_a[m,n] = bias_z[n] + sum_s s16[m,s]*T2t[n,s]; s16 from split-K P partials.
// ---------------------------------------------------------------------------
__global__ __launch_bounds__(256) void za_kernel(
    const bf16* __restrict__ P0, const bf16* __restrict__ P1,
    const float* __restrict__ T2t,
    const float* __restrict__ cvec, const float* __restrict__ bias_z,
    bf16* __restrict__ z)
{
  __shared__ float s16t[32][16];
  const int tid = threadIdx.x;
  const int tok0 = blockIdx.x * 32;
  for (int p = tid; p < 512; p += 256) {
    const int t = p >> 4, s = p & 15;
    const int tok = tok0 + t;
    const int l = tok & (SEQ - 1), bb = tok >> 12;
    float acc = cvec[s];
#pragma unroll
    for (int k = 0; k < 4; ++k) {
      const int r = l - 1 + k;
      if ((unsigned)r < (unsigned)SEQ) {
        const size_t idx = ((size_t)bb * SEQ + r) * 128 + k * 16 + s;
        acc += (float)P0[idx] + (float)P1[idx];
      }
    }
    s16t[t][s] = acc;
  }
  const int c0 = tid * 8;
  float t2[8][16], bz[8];
#pragma unroll
  for (int j = 0; j < 8; ++j) {
    bz[j] = bias_z[c0 + j];
#pragma unroll
    for (int q = 0; q < 4; ++q) {
      float4 v = ((const float4*)(T2t + (size_t)(c0 + j) * 16))[q];
      t2[j][q * 4 + 0] = v.x; t2[j][q * 4 + 1] = v.y;
      t2[j][q * 4 + 2] = v.z; t2[j][q * 4 + 3] = v.w;
    }
  }
  __syncthreads();
  for (int t = 0; t < 32; ++t) {
    float sv[16];
#pragma unroll
    for (int s = 0; s < 16; ++s) sv[s] = s16t[t][s];
    bf16x8 o;
#pragma unroll
    for (int j = 0; j < 8; ++j) {
      float a = bz[j];
#pragma unroll
      for (int s = 0; s < 16; ++s) a += sv[s] * t2[j][s];
      o[j] = (bf16)a;
    }
    *(bf16x8*)(z + (size_t)(tok0 + t) * 2048 + c0) = o;
  }
}

// ---------------------------------------------------------------------------
extern "C" void kernel_launch(void* const* d_in, const int* in_sizes, int n_in,
                              void* d_out, int out_size, void* d_ws, size_t ws_size,
                              hipStream_t stream)
{
  const float* x      = (const float*)d_in[0];
  const float* norm_w = (const float*)d_in[1];
  const float* in_w   = (const float*)d_in[2];
  const float* in_b   = (const float*)d_in[3];
  const float* dwa_k  = (const float*)d_in[4];
  const float* dwa_b  = (const float*)d_in[5];
  const float* Amat   = (const float*)d_in[6];
  const float* Bm     = (const float*)d_in[7];
  const float* sym_k  = (const float*)d_in[8];
  const float* sym_b  = (const float*)d_in[9];
  const float* pw_w   = (const float*)d_in[10];
  const float* pw_b   = (const float*)d_in[11];
  const float* ha_w   = (const float*)d_in[12];
  const float* ha_b   = (const float*)d_in[13];
  const float* hb_w   = (const float*)d_in[14];
  const float* hb_b   = (const float*)d_in[15];
  const float* fuse_w = (const float*)d_in[16];
  const float* fuse_b = (const float*)d_in[17];
  const float* out_w  = (const float*)d_in[18];
  const float* out_b  = (const float*)d_in[19];
  float* out = (float*)d_out;

  char* ws = (char*)d_ws;
  const size_t MB = 1u << 20, KB = 1u << 10;
  bf16*  in_wbf  = (bf16*)(ws + 0);
  bf16*  hnorm   = (bf16*)(ws + 8 * MB);
  bf16*  bsilu   = (bf16*)(ws + 0);
  bf16*  valp    = (bf16*)(ws + 64 * MB);
  bf16*  zbuf    = (bf16*)(ws + 64 * MB);
  bf16*  gatep   = (bf16*)(ws + 128 * MB);
  bf16*  Pbuf    = (bf16*)(ws + 192 * MB);
  bf16*  pwT_bf  = (bf16*)(ws + 200 * MB);
  bf16*  WB_bf   = (bf16*)(ws + 200 * MB);
  bf16*  hb_bf   = (bf16*)(ws + 208 * MB);
  bf16*  Fb_bf   = (bf16*)(ws + 208 * MB);
  bf16*  Ht_bf   = (bf16*)(ws + 212 * MB);
  bf16*  out_bf  = (bf16*)(ws + 216 * MB);
  float* T1      = (float*)(ws + 220 * MB);
  float* cvec    = (float*)(ws + 220 * MB + 64 * KB);
  float* b_H     = (float*)(ws + 220 * MB + 68 * KB);
  float* bias_z  = (float*)(ws + 220 * MB + 72 * KB);
  bf16*  Wp      = (bf16*)(ws + 220 * MB + 80 * KB);
  float* T2t     = (float*)(ws + 220 * MB + 592 * KB);

  // ---- weight prep ----
  prep_cvt_kernel<<<8192, 256, 0, stream>>>(in_w, hb_w, out_w, in_wbf, hb_bf, out_bf);
  transpose_kernel<<<dim3(64, 64), 256, 0, stream>>>(pw_w, pwT_bf);
  gemm_bt<EPI_PLAIN><<<dim3(8, 16), 256, 0, stream>>>(
      pwT_bf, hb_bf, nullptr, Ht_bf, nullptr, nullptr, nullptr, nullptr, 1024, 2048, 1024, 0);
  prep_small_kernel<<<3085, 256, 0, stream>>>(
      Bm, ha_w, dwa_b, dwa_k, Amat, hb_w, pw_b, hb_b, fuse_w,
      T1, cvec, b_H, Wp, Fb_bf);
  gemm_bt<EPI_PLAIN><<<dim3(16, 16), 256, 0, stream>>>(
      Fb_bf, Ht_bf, nullptr, WB_bf, nullptr, nullptr, nullptr, nullptr, 2048, 1024, 2048, 0);
  prep_fuse_kernel<<<136, 256, 0, stream>>>(T1, fuse_w, fuse_b, ha_b, b_H, T2t, bias_z);

  // ---- main chain ----
  rmsnorm_kernel<<<MTOK, 256, 0, stream>>>(x, norm_w, hnorm);
  // in-proj (256^2 8-phase): gate = sigmoid(h[:, :DI]), val = h[:, DI:]
  gemm256<EPI_SPLIT><<<dim3(16, 64), 512, 0, stream>>>(
      hnorm, in_wbf, in_b, gatep, valp, nullptr, nullptr, nullptr, 1024, DI);
  conv_kernel<<<dim3(SEQ / TL2, 2, BATCH), 256, 0, stream>>>(
      valp, sym_k, sym_b, bsilu);
  gemm_bt<EPI_PLAIN, true><<<dim3(2, 128), 256, 0, stream>>>(
      valp, Wp, nullptr, Pbuf, nullptr, nullptr, nullptr, nullptr, 128, 2048, 128, 0);
  za_kernel<<<MTOK / 32, 256, 0, stream>>>(
      Pbuf, Pbuf + (size_t)MTOK * 128, T2t, cvec, bias_z, zbuf);
  // B-GEMM (256^2 8-phase): y2 = gate * (bsilu @ W_B^T + z_a)  [in-place]
  gemm256<EPI_GATEADD><<<dim3(8, 64), 512, 0, stream>>>(
      bsilu, WB_bf, nullptr, zbuf, nullptr, gatep, nullptr, nullptr, 2048, 2048);
  // out GEMM (256^2 8-phase) + residual -> fp32 d_out
  gemm256<EPI_RES><<<dim3(4, 64), 512, 0, stream>>>(
      zbuf, out_bf, out_b, nullptr, nullptr, nullptr, out, x, 2048, 1024);
}

// Round 3
// 936.585 us; speedup vs baseline: 1.0897x; 1.0897x over previous
//
#include <hip/hip_runtime.h>
#include <hip/hip_bf16.h>
#include <stdint.h>

typedef __bf16 bf16;
typedef __bf16 bf16x8 __attribute__((ext_vector_type(8)));
typedef __bf16 bf16x4 __attribute__((ext_vector_type(4)));
typedef float  f32x4  __attribute__((ext_vector_type(4)));

#define LDS_PTR(p) ((__attribute__((address_space(3))) uint32_t*)(p))
#define GLB_PTR(p) ((const __attribute__((address_space(1))) uint32_t*)(p))

static constexpr int BATCH = 4, SEQ = 4096, DMODEL = 1024;
static constexpr int DI = 2048;
static constexpr int MTOK = BATCH * SEQ;   // 16384 tokens

enum { EPI_SPLIT = 0, EPI_PLAIN = 1, EPI_GATEADD = 2, EPI_RES = 3 };

// ---------------------------------------------------------------------------
// 128x128-tile bf16 GEMM (m97 structure) — kept for the small prep GEMMs
// and the skinny split-K P GEMM.
// ---------------------------------------------------------------------------
template <int EPI, bool SPLITK = false>
__global__ __launch_bounds__(256) void gemm_bt(
    const bf16* __restrict__ Aact, const bf16* __restrict__ W,
    const float* __restrict__ bias,
    bf16* __restrict__ out0, bf16* __restrict__ out1,
    const bf16* __restrict__ gate,
    float* __restrict__ outf, const float* __restrict__ resid,
    int N, int K, int ldC, int col_off)
{
  __shared__ __align__(16) bf16 sA[128 * 64];
  __shared__ __align__(16) bf16 sB[128 * 64];
  const int tid  = threadIdx.x;
  int n0, m0, kbeg, kend;
  size_t out_off = 0;
  if (SPLITK) {
    n0 = 0; m0 = blockIdx.y * 128;
    const int kh = K / gridDim.x;
    kbeg = blockIdx.x * kh; kend = kbeg + kh;
    out_off = (size_t)blockIdx.x * ((size_t)MTOK * 128);
  } else {
    const int nT  = gridDim.x;
    const int lin = blockIdx.y * nT + blockIdx.x;
    const int grp = lin / (8 * nT);
    const int within = lin - grp * (8 * nT);
    n0 = (within >> 3) * 128;
    m0 = (grp * 8 + (within & 7)) * 128;
    kbeg = 0; kend = K;
  }
  const int lane = tid & 63;
  const int wv   = tid >> 6;
  const int wr   = wv >> 1, wc = wv & 1;
  const int l15  = lane & 15, quad = lane >> 4;

  f32x4 acc[4][4];
#pragma unroll
  for (int i = 0; i < 4; ++i)
#pragma unroll
    for (int j = 0; j < 4; ++j) acc[i][j] = (f32x4){0.f, 0.f, 0.f, 0.f};

  int rr[4], cb[4];
#pragma unroll
  for (int j = 0; j < 4; ++j) {
    const int s = tid + j * 256;
    rr[j] = s >> 3;
    cb[j] = ((s & 7) ^ (rr[j] & 7)) * 16;
  }

  const char* gA = (const char*)(Aact + (size_t)m0 * K);
  const char* gW = (const char*)(W + (size_t)n0 * K);

  for (int k0 = kbeg; k0 < kend; k0 += 64) {
    if (k0 != kbeg) __syncthreads();
#pragma unroll
    for (int j = 0; j < 4; ++j)
      __builtin_amdgcn_global_load_lds(GLB_PTR(gA + ((size_t)rr[j] * K + k0) * 2 + cb[j]),
                                       LDS_PTR(sA + (tid + j * 256) * 8), 16, 0, 0);
#pragma unroll
    for (int j = 0; j < 4; ++j)
      __builtin_amdgcn_global_load_lds(GLB_PTR(gW + ((size_t)rr[j] * K + k0) * 2 + cb[j]),
                                       LDS_PTR(sB + (tid + j * 256) * 8), 16, 0, 0);
    __syncthreads();

#pragma unroll
    for (int h = 0; h < 2; ++h) {
      bf16x8 av[4], bv[4];
#pragma unroll
      for (int t = 0; t < 4; ++t) {
        const int Ra = wr * 64 + t * 16 + l15;
        const int Rb = wc * 64 + t * 16 + l15;
        const int cc = h * 4 + quad;
        av[t] = *(const bf16x8*)(sA + (Ra * 8 + (cc ^ (Ra & 7))) * 8);
        bv[t] = *(const bf16x8*)(sB + (Rb * 8 + (cc ^ (Rb & 7))) * 8);
      }
#pragma unroll
      for (int i = 0; i < 4; ++i)
#pragma unroll
        for (int j = 0; j < 4; ++j)
          acc[i][j] = __builtin_amdgcn_mfma_f32_16x16x32_bf16(av[i], bv[j], acc[i][j], 0, 0, 0);
    }
  }

  bf16* o0 = out0 + out_off;
#pragma unroll
  for (int i = 0; i < 4; ++i) {
    const int mbase = m0 + wr * 64 + i * 16 + quad * 4;
#pragma unroll
    for (int j = 0; j < 4; ++j) {
      const int n = n0 + wc * 64 + j * 16 + l15;
      const float bj = bias ? bias[n] : 0.f;
#pragma unroll
      for (int r = 0; r < 4; ++r) {
        const int mm = mbase + r;
        float v = acc[i][j][r] + bj;
        if (EPI == EPI_SPLIT) {
          if (n < DI) o0[(size_t)mm * DI + n] = (bf16)(1.f / (1.f + __expf(-v)));
          else        out1[(size_t)mm * DI + (n - DI)] = (bf16)v;
        } else if (EPI == EPI_PLAIN) {
          o0[(size_t)mm * ldC + col_off + n] = (bf16)v;
        } else if (EPI == EPI_GATEADD) {
          const size_t idx = (size_t)mm * ldC + n;
          float zz = (float)o0[idx];
          float g  = (float)gate[(size_t)mm * DI + n];
          o0[idx] = (bf16)((v + zz) * g);
        } else {
          outf[(size_t)mm * ldC + n] = v + resid[(size_t)mm * ldC + n];
        }
      }
    }
  }
}

// ---------------------------------------------------------------------------
// 256x256-tile, 8-wave bf16 GEMM — m201-faithful geometry.
//   WARPS 2M x 4N: per-wave output 128x64 (8 m-frags x 4 n-frags).
//   4 phases per K-tile (BK=64) = accumulator quadrants in order
//   (qm0,qn0) (qm0,qn1) (qm1,qn1) (qm1,qn0); fragment reads per tile
//   12/4/8/0 ds_read_b128 (A-frags reused across qn, B-frags across qm)
//   = 24 reads per 64 MFMA (0.375).
//   Staging (2 global_load_lds per half-tile per thread):
//     ph1(t): A.h1,B.h1 of tile t+1 -> nxt buffer (regions last read ph<=4(t-1))
//     ph4(t): A.h0,B.h0 of tile t+2 -> cur buffer (h0 regions die at ph3(t))
//   ONE counted vmcnt(4) per tile at ph4: queue=12, retires the 4 half-tiles
//   tile t+1 reads (leads 3-4 phases), retains the 2 just issued. Never
//   drains in the main loop. Tail stages wrap to k=0 (harmless).
// LDS swizzle identical to gemm_bt (measured 0 conflicts).
// ---------------------------------------------------------------------------
#define G256_STAGE(gmat, smat, dstoff, half, k0)                                  \
  do {                                                                            \
    const char* _g = (gmat) + ((size_t)((half) * 128 + r0) * K + (size_t)(k0)) * 2 + c0; \
    const int _d = (dstoff) + (half) * 8192 + tid * 8;                            \
    __builtin_amdgcn_global_load_lds(GLB_PTR(_g), LDS_PTR((smat) + _d), 16, 0, 0); \
    __builtin_amdgcn_global_load_lds(GLB_PTR(_g + (size_t)128 * K),               \
                                     LDS_PTR((smat) + _d + 4096), 16, 0, 0);      \
  } while (0)

#define RD_A(dst, ROWBASE)                                                        \
  _Pragma("unroll")                                                               \
  for (int kk = 0; kk < 2; ++kk) {                                                \
    _Pragma("unroll")                                                             \
    for (int i = 0; i < 4; ++i) {                                                 \
      const int R = (ROWBASE) + i * 16 + l15;                                     \
      const int cc = kk * 4 + quad;                                               \
      dst[kk][i] = *(const bf16x8*)(sA + cur + (R >> 7) * 8192 +                  \
                                    ((R & 127) * 8 + (cc ^ (R & 7))) * 8);        \
    }                                                                             \
  }

#define RD_B(dst, ROWBASE)                                                        \
  _Pragma("unroll")                                                               \
  for (int kk = 0; kk < 2; ++kk) {                                                \
    _Pragma("unroll")                                                             \
    for (int j = 0; j < 2; ++j) {                                                 \
      const int R = (ROWBASE) + j * 16 + l15;                                     \
      const int cc = kk * 4 + quad;                                               \
      dst[kk][j] = *(const bf16x8*)(sB + cur + (R >> 7) * 8192 +                  \
                                    ((R & 127) * 8 + (cc ^ (R & 7))) * 8);        \
    }                                                                             \
  }

#define MF16(AV, BV, I0, J0)                                                      \
  __builtin_amdgcn_s_setprio(1);                                                  \
  _Pragma("unroll")                                                               \
  for (int kk = 0; kk < 2; ++kk)                                                  \
    _Pragma("unroll")                                                             \
    for (int i = 0; i < 4; ++i)                                                   \
      _Pragma("unroll")                                                           \
      for (int j = 0; j < 2; ++j)                                                 \
        acc[(I0) + i][(J0) + j] = __builtin_amdgcn_mfma_f32_16x16x32_bf16(        \
            AV[kk][i], BV[kk][j], acc[(I0) + i][(J0) + j], 0, 0, 0);              \
  __builtin_amdgcn_s_setprio(0);

#define BAR_LGKM                                                                  \
  __builtin_amdgcn_s_barrier();                                                   \
  asm volatile("s_waitcnt lgkmcnt(0)" ::: "memory");                              \
  __builtin_amdgcn_sched_barrier(0);

#define PH_END                                                                    \
  __builtin_amdgcn_sched_barrier(0);                                              \
  __builtin_amdgcn_s_barrier();                                                   \
  __builtin_amdgcn_sched_barrier(0);

template <int EPI>
__global__ __launch_bounds__(512, 2) void gemm256(
    const bf16* __restrict__ Aact, const bf16* __restrict__ W,
    const float* __restrict__ bias,
    bf16* __restrict__ out0, bf16* __restrict__ out1,
    const bf16* __restrict__ gate,
    float* __restrict__ outf, const float* __restrict__ resid,
    int K, int ldC)
{
  __shared__ __align__(16) bf16 sA[2 * 16384];   // 2 buf x 256 rows x 64 k
  __shared__ __align__(16) bf16 sB[2 * 16384];
  const int tid = threadIdx.x;

  // GM=8 m-group swizzle: each XCD sweeps n at a fixed m-group (L2 locality)
  const int nT  = gridDim.x;
  const int lin = blockIdx.y * nT + blockIdx.x;
  const int grp = lin / (8 * nT);
  const int within = lin - grp * (8 * nT);
  const int n0 = (within >> 3) * 256;
  const int m0 = (grp * 8 + (within & 7)) * 256;

  const int lane = tid & 63;
  const int wv   = tid >> 6;        // 0..7
  const int wr   = wv >> 2;         // 0..1 : 128-row slice
  const int wc   = wv & 3;          // 0..3 : 64-col slice
  const int l15  = lane & 15, quad = lane >> 4;

  f32x4 acc[8][4];
#pragma unroll
  for (int i = 0; i < 8; ++i)
#pragma unroll
    for (int j = 0; j < 4; ++j) acc[i][j] = (f32x4){0.f, 0.f, 0.f, 0.f};

  // staging geometry: 1024 16B chunks per half-tile, 2 per thread
  const int r0 = tid >> 3;
  const int c0 = ((tid & 7) ^ (r0 & 7)) * 16;   // (r0+64)&7 == r0&7

  const char* gA = (const char*)(Aact + (size_t)m0 * K);
  const char* gW = (const char*)(W + (size_t)n0 * K);

  const int NT = K >> 6;

  // prologue: tile0 all 4 half-tiles + tile1 h0 pair; confirm tile0 (keep 4)
  G256_STAGE(gA, sA, 0, 0, 0);
  G256_STAGE(gW, sB, 0, 0, 0);
  G256_STAGE(gA, sA, 0, 1, 0);
  G256_STAGE(gW, sB, 0, 1, 0);
  G256_STAGE(gA, sA, 16384, 0, 64);
  G256_STAGE(gW, sB, 16384, 0, 64);
  asm volatile("s_waitcnt vmcnt(4)" ::: "memory");
  __builtin_amdgcn_s_barrier();

  int cur = 0;
  for (int t = 0; t < NT; ++t) {
    const int kn1 = (t + 1 < NT ? t + 1 : 0) * 64;
    const int kn2 = (t + 2 < NT ? t + 2 : t + 2 - NT) * 64;
    const int nxt = cur ^ 16384;
    bf16x8 av0[2][4], av1[2][4], bv0[2][2], bv1[2][2];

    // ---- phase 1: (qm0,qn0) — read av0(8)+bv0(4), stage t+1 h1 pair ----
    RD_A(av0, wr * 128);
    RD_B(bv0, wc * 64);
    G256_STAGE(gA, sA, nxt, 1, kn1);
    G256_STAGE(gW, sB, nxt, 1, kn1);
    BAR_LGKM;
    MF16(av0, bv0, 0, 0);
    PH_END;

    // ---- phase 2: (qm0,qn1) — read bv1(4), reuse av0 ----
    RD_B(bv1, wc * 64 + 32);
    BAR_LGKM;
    MF16(av0, bv1, 0, 2);
    PH_END;

    // ---- phase 3: (qm1,qn1) — read av1(8), reuse bv1 ----
    RD_A(av1, wr * 128 + 64);
    BAR_LGKM;
    MF16(av1, bv1, 4, 2);
    PH_END;

    // ---- phase 4: (qm1,qn0) — no reads, stage t+2 h0 pair, counted wait ----
    G256_STAGE(gA, sA, cur, 0, kn2);
    G256_STAGE(gW, sB, cur, 0, kn2);
    asm volatile("s_waitcnt vmcnt(4)" ::: "memory");
    __builtin_amdgcn_s_barrier();
    __builtin_amdgcn_sched_barrier(0);
    MF16(av1, bv0, 4, 0);
    PH_END;

    cur = nxt;
  }
  asm volatile("s_waitcnt vmcnt(0)" ::: "memory");

  // epilogue: C/D layout col = lane&15, row = quad*4 + r (m89-verified)
#pragma unroll
  for (int ifr = 0; ifr < 8; ++ifr) {
    const int mbase = m0 + wr * 128 + ifr * 16 + quad * 4;
#pragma unroll
    for (int jfr = 0; jfr < 4; ++jfr) {
      const int n = n0 + wc * 64 + jfr * 16 + l15;
      const float bj = bias ? bias[n] : 0.f;
#pragma unroll
      for (int r = 0; r < 4; ++r) {
        const int mm = mbase + r;
        float v = acc[ifr][jfr][r] + bj;
        if (EPI == EPI_SPLIT) {
          if (n < DI) out0[(size_t)mm * DI + n] = (bf16)(1.f / (1.f + __expf(-v)));
          else        out1[(size_t)mm * DI + (n - DI)] = (bf16)v;
        } else if (EPI == EPI_GATEADD) {
          const size_t idx = (size_t)mm * ldC + n;
          float zz = (float)out0[idx];
          float g  = (float)gate[(size_t)mm * DI + n];
          out0[idx] = (bf16)((v + zz) * g);
        } else {  // EPI_RES
          outf[(size_t)mm * ldC + n] = v + resid[(size_t)mm * ldC + n];
        }
      }
    }
  }
}

// ---------------------------------------------------------------------------
// RMSNorm: one block per token row (1024 fp32 -> 1024 bf16)
// ---------------------------------------------------------------------------
__global__ __launch_bounds__(256) void rmsnorm_kernel(
    const float* __restrict__ x, const float* __restrict__ w, bf16* __restrict__ out)
{
  const int row = blockIdx.x;
  const int tid = threadIdx.x;
  const float4 xv = ((const float4*)(x + (size_t)row * DMODEL))[tid];
  float s = xv.x * xv.x + xv.y * xv.y + xv.z * xv.z + xv.w * xv.w;
#pragma unroll
  for (int o = 32; o; o >>= 1) s += __shfl_xor(s, o);
  __shared__ float red[4];
  if ((tid & 63) == 0) red[tid >> 6] = s;
  __syncthreads();
  const float tot = red[0] + red[1] + red[2] + red[3];
  const float scale = rsqrtf(tot * (1.f / DMODEL) + 1e-6f);
  const float4 wv = ((const float4*)w)[tid];
  bf16x4 o4 = { (bf16)(xv.x * wv.x * scale), (bf16)(xv.y * wv.y * scale),
                (bf16)(xv.z * wv.z * scale), (bf16)(xv.w * wv.w * scale) };
  *(bf16x4*)(out + (size_t)row * DMODEL + tid * 4) = o4;
}

// ---------------------------------------------------------------------------
// 9-tap depthwise conv + silu, 4 channels/thread (bf16x4 loads).
// ---------------------------------------------------------------------------
static constexpr int TL2 = 64;
__global__ __launch_bounds__(256) void conv_kernel(
    const bf16* __restrict__ val,
    const float* __restrict__ sym_k, const float* __restrict__ sym_b,
    bf16* __restrict__ bbuf)
{
  const int d  = (blockIdx.y * 256 + threadIdx.x) * 4;
  const int b  = blockIdx.z;
  const int l0 = blockIdx.x * TL2;
  float wk[9][4], bs[4];
#pragma unroll
  for (int j = 0; j < 4; ++j) {
    bs[j] = sym_b[d + j];
#pragma unroll
    for (int k = 0; k < 9; ++k) wk[k][j] = sym_k[(d + j) * 9 + k];
  }
  const bf16* base = val + (size_t)b * SEQ * DI + d;

  float win[9][4];
#pragma unroll
  for (int j = 0; j < 8; ++j) {
    const int xr = l0 + j - 4;
    if (xr >= 0 && xr < SEQ) {
      bf16x4 v = *(const bf16x4*)(base + (size_t)xr * DI);
#pragma unroll
      for (int c = 0; c < 4; ++c) win[j][c] = (float)v[c];
    } else {
#pragma unroll
      for (int c = 0; c < 4; ++c) win[j][c] = 0.f;
    }
  }
  for (int t = 0; t < TL2; ++t) {
    const int xf = l0 + t + 4;
    if (xf < SEQ) {
      bf16x4 v = *(const bf16x4*)(base + (size_t)xf * DI);
#pragma unroll
      for (int c = 0; c < 4; ++c) win[8][c] = (float)v[c];
    } else {
#pragma unroll
      for (int c = 0; c < 4; ++c) win[8][c] = 0.f;
    }
    float sb[4];
#pragma unroll
    for (int c = 0; c < 4; ++c) sb[c] = bs[c];
#pragma unroll
    for (int k = 0; k < 9; ++k)
#pragma unroll
      for (int c = 0; c < 4; ++c) sb[c] += win[k][c] * wk[k][c];
    bf16x4 o;
#pragma unroll
    for (int c = 0; c < 4; ++c) o[c] = (bf16)(sb[c] / (1.f + __expf(-sb[c])));
    *(bf16x4*)(bbuf + ((size_t)b * SEQ + l0 + t) * DI + d) = o;
#pragma unroll
    for (int k = 0; k < 8; ++k)
#pragma unroll
      for (int c = 0; c < 4; ++c) win[k][c] = win[k + 1][c];
  }
}

// ---------------------------------------------------------------------------
// prep_cvt: merged fp32->bf16 conversions (in_w, hb_w, out_w)
// ---------------------------------------------------------------------------
__global__ __launch_bounds__(256) void prep_cvt_kernel(
    const float* __restrict__ in_w, const float* __restrict__ hb_w,
    const float* __restrict__ out_w,
    bf16* __restrict__ in_wbf, bf16* __restrict__ hb_bf, bf16* __restrict__ out_bf)
{
  const int b = blockIdx.x;
  const float* src; bf16* dst; size_t i;
  if (b < 4096)      { src = in_w;  dst = in_wbf; i = (size_t)b * 256 + threadIdx.x; }
  else if (b < 6144) { src = hb_w;  dst = hb_bf;  i = (size_t)(b - 4096) * 256 + threadIdx.x; }
  else               { src = out_w; dst = out_bf; i = (size_t)(b - 6144) * 256 + threadIdx.x; }
  const float4 v = ((const float4*)src)[i];
  bf16x4 o4 = { (bf16)v.x, (bf16)v.y, (bf16)v.z, (bf16)v.w };
  *(bf16x4*)(dst + 4 * i) = o4;
}

// pwT_bf[d][c] = (bf16)pw_w[c][d]   (2048x2048 transpose via LDS)
__global__ __launch_bounds__(256) void transpose_kernel(
    const float* __restrict__ in, bf16* __restrict__ out)
{
  __shared__ float s[32][33];
  const int tid = threadIdx.x;
  const int r = tid >> 5, x = tid & 31;
  const int c0 = blockIdx.y * 32, d0 = blockIdx.x * 32;
#pragma unroll
  for (int rr = r; rr < 32; rr += 8)
    s[rr][x] = in[(size_t)(c0 + rr) * 2048 + d0 + x];
  __syncthreads();
#pragma unroll
  for (int rr = r; rr < 32; rr += 8)
    out[(size_t)(d0 + rr) * 2048 + c0 + x] = (bf16)s[x][rr];
}

// ---------------------------------------------------------------------------
// prep_small: t1 (1024) | cvec (1) | bh (4) | wprep (8) | fbcopy (2048)
// ---------------------------------------------------------------------------
__global__ __launch_bounds__(256) void prep_small_kernel(
    const float* __restrict__ Bm, const float* __restrict__ ha_w,
    const float* __restrict__ dwa_b, const float* __restrict__ dwa_k,
    const float* __restrict__ A,
    const float* __restrict__ hb_w, const float* __restrict__ pw_b,
    const float* __restrict__ hb_b, const float* __restrict__ fuse_w,
    float* __restrict__ T1, float* __restrict__ cvec, float* __restrict__ b_H,
    bf16* __restrict__ Wp, bf16* __restrict__ Fb)
{
  const int b = blockIdx.x, tid = threadIdx.x;
  __shared__ float red[4][16];
  if (b < 1024) {
    const int o = b;
    float acc[16];
#pragma unroll
    for (int s = 0; s < 16; ++s) acc[s] = 0.f;
    for (int d = tid; d < 2048; d += 256) {
      const float w = ha_w[(size_t)o * 2048 + d];
#pragma unroll
      for (int s = 0; s < 16; ++s) acc[s] += Bm[s * 2048 + d] * w;
    }
    const int lane = tid & 63, wv = tid >> 6;
#pragma unroll
    for (int s = 0; s < 16; ++s) {
      float v = acc[s];
#pragma unroll
      for (int off = 32; off; off >>= 1) v += __shfl_xor(v, off);
      if (lane == s) red[wv][s] = v;
    }
    __syncthreads();
    if (tid < 16)
      T1[tid * 1024 + o] = red[0][tid] + red[1][tid] + red[2][tid] + red[3][tid];
  } else if (b == 1024) {
    float acc[16];
#pragma unroll
    for (int s = 0; s < 16; ++s) acc[s] = 0.f;
    for (int d = tid; d < 2048; d += 256) {
      const float w = dwa_b[d];
#pragma unroll
      for (int s = 0; s < 16; ++s) acc[s] += w * A[d * 16 + s];
    }
    const int lane = tid & 63, wv = tid >> 6;
#pragma unroll
    for (int s = 0; s < 16; ++s) {
      float v = acc[s];
#pragma unroll
      for (int off = 32; off; off >>= 1) v += __shfl_xor(v, off);
      if (lane == s) red[wv][s] = v;
    }
    __syncthreads();
    if (tid < 16) cvec[tid] = red[0][tid] + red[1][tid] + red[2][tid] + red[3][tid];
  } else if (b < 1029) {
    const int o = (b - 1025) * 256 + tid;
    float acc = hb_b[o];
    const float* hr = hb_w + (size_t)o * 2048;
    for (int c = 0; c < 2048; c += 4) {
      float4 h = *(const float4*)(hr + c);
      float4 p = *(const float4*)(pw_b + c);
      acc += h.x * p.x + h.y * p.y + h.z * p.z + h.w * p.w;
    }
    b_H[o] = acc;
  } else if (b < 1037) {
    const int d = (b - 1029) * 256 + tid;
    float kk[4], av[16];
#pragma unroll
    for (int k = 0; k < 4; ++k) kk[k] = dwa_k[d * 4 + k];
#pragma unroll
    for (int s = 0; s < 16; ++s) av[s] = A[d * 16 + s];
#pragma unroll
    for (int k = 0; k < 4; ++k)
#pragma unroll
      for (int s = 0; s < 16; ++s)
        Wp[(size_t)(k * 16 + s) * 2048 + d] = (bf16)(kk[k] * av[s]);
    for (int n = 64; n < 128; ++n) Wp[(size_t)n * 2048 + d] = (bf16)0.f;
  } else {
    const int idx = (b - 1037) * 256 + tid;
    const int n = idx >> 8, o4 = idx & 255;
    float4 v = ((const float4*)(fuse_w + (size_t)n * 2048 + 1024))[o4];
    bf16x4 o = { (bf16)v.x, (bf16)v.y, (bf16)v.z, (bf16)v.w };
    *(bf16x4*)(Fb + (size_t)n * 1024 + o4 * 4) = o;
  }
}

// ---------------------------------------------------------------------------
// prep_fuse: t2t (128 blocks) | biasz (8 blocks). Needs T1 and b_H.
// ---------------------------------------------------------------------------
__global__ __launch_bounds__(256) void prep_fuse_kernel(
    const float* __restrict__ T1, const float* __restrict__ fuse_w,
    const float* __restrict__ fuse_b, const float* __restrict__ ha_b,
    const float* __restrict__ b_H,
    float* __restrict__ T2t, float* __restrict__ bias_z)
{
  const int b = blockIdx.x, tid = threadIdx.x;
  if (b < 128) {
    const int n = b * 16 + (tid >> 4);
    const int s = tid & 15;
    const float* fr = fuse_w + (size_t)n * 2048;
    const float* tr = T1 + s * 1024;
    float acc = 0.f;
    for (int o = 0; o < 1024; o += 4) {
      float4 f = *(const float4*)(fr + o);
      float4 t = *(const float4*)(tr + o);
      acc += f.x * t.x + f.y * t.y + f.z * t.z + f.w * t.w;
    }
    T2t[n * 16 + s] = acc;
  } else {
    const int n = (b - 128) * 256 + tid;
    float acc = fuse_b[n];
    const float* fr = fuse_w + (size_t)n * 2048;
    for (int o = 0; o < 1024; o += 4) {
      float4 fa = *(const float4*)(fr + o);
      float4 fb = *(const float4*)(fr + 1024 + o);
      float4 ha = *(const float4*)(ha_b + o);
      float4 bh = *(const float4*)(b_H + o);
      acc += fa.x * ha.x + fa.y * ha.y + fa.z * ha.z + fa.w * ha.w;
      acc += fb.x * bh.x + fb.y * bh.y + fb.z * bh.z + fb.w * bh.w;
    }
    bias_z[n] = acc;
  }
}

// ---------------------------------------------------------------------------
// z_a[m,n] = bias_z[n] + sum_s s16[m,s]*T2t[n,s]; s16 from split-K P partials.
// ---------------------------------------------------------------------------
__global__ __launch_bounds__(256) void za_kernel(
    const bf16* __restrict__ P0, const bf16* __restrict__ P1,
    const float* __restrict__ T2t,
    const float* __restrict__ cvec, const float* __restrict__ bias_z,
    bf16* __restrict__ z)
{
  __shared__ float s16t[32][16];
  const int tid = threadIdx.x;
  const int tok0 = blockIdx.x * 32;
  for (int p = tid; p < 512; p += 256) {
    const int t = p >> 4, s = p & 15;
    const int tok = tok0 + t;
    const int l = tok & (SEQ - 1), bb = tok >> 12;
    float acc = cvec[s];
#pragma unroll
    for (int k = 0; k < 4; ++k) {
      const int r = l - 1 + k;
      if ((unsigned)r < (unsigned)SEQ) {
        const size_t idx = ((size_t)bb * SEQ + r) * 128 + k * 16 + s;
        acc += (float)P0[idx] + (float)P1[idx];
      }
    }
    s16t[t][s] = acc;
  }
  const int c0 = tid * 8;
  float t2[8][16], bz[8];
#pragma unroll
  for (int j = 0; j < 8; ++j) {
    bz[j] = bias_z[c0 + j];
#pragma unroll
    for (int q = 0; q < 4; ++q) {
      float4 v = ((const float4*)(T2t + (size_t)(c0 + j) * 16))[q];
      t2[j][q * 4 + 0] = v.x; t2[j][q * 4 + 1] = v.y;
      t2[j][q * 4 + 2] = v.z; t2[j][q * 4 + 3] = v.w;
    }
  }
  __syncthreads();
  for (int t = 0; t < 32; ++t) {
    float sv[16];
#pragma unroll
    for (int s = 0; s < 16; ++s) sv[s] = s16t[t][s];
    bf16x8 o;
#pragma unroll
    for (int j = 0; j < 8; ++j) {
      float a = bz[j];
#pragma unroll
      for (int s = 0; s < 16; ++s) a += sv[s] * t2[j][s];
      o[j] = (bf16)a;
    }
    *(bf16x8*)(z + (size_t)(tok0 + t) * 2048 + c0) = o;
  }
}

// ---------------------------------------------------------------------------
extern "C" void kernel_launch(void* const* d_in, const int* in_sizes, int n_in,
                              void* d_out, int out_size, void* d_ws, size_t ws_size,
                              hipStream_t stream)
{
  const float* x      = (const float*)d_in[0];
  const float* norm_w = (const float*)d_in[1];
  const float* in_w   = (const float*)d_in[2];
  const float* in_b   = (const float*)d_in[3];
  const float* dwa_k  = (const float*)d_in[4];
  const float* dwa_b  = (const float*)d_in[5];
  const float* Amat   = (const float*)d_in[6];
  const float* Bm     = (const float*)d_in[7];
  const float* sym_k  = (const float*)d_in[8];
  const float* sym_b  = (const float*)d_in[9];
  const float* pw_w   = (const float*)d_in[10];
  const float* pw_b   = (const float*)d_in[11];
  const float* ha_w   = (const float*)d_in[12];
  const float* ha_b   = (const float*)d_in[13];
  const float* hb_w   = (const float*)d_in[14];
  const float* hb_b   = (const float*)d_in[15];
  const float* fuse_w = (const float*)d_in[16];
  const float* fuse_b = (const float*)d_in[17];
  const float* out_w  = (const float*)d_in[18];
  const float* out_b  = (const float*)d_in[19];
  float* out = (float*)d_out;

  char* ws = (char*)d_ws;
  const size_t MB = 1u << 20, KB = 1u << 10;
  bf16*  in_wbf  = (bf16*)(ws + 0);
  bf16*  hnorm   = (bf16*)(ws + 8 * MB);
  bf16*  bsilu   = (bf16*)(ws + 0);
  bf16*  valp    = (bf16*)(ws + 64 * MB);
  bf16*  zbuf    = (bf16*)(ws + 64 * MB);
  bf16*  gatep   = (bf16*)(ws + 128 * MB);
  bf16*  Pbuf    = (bf16*)(ws + 192 * MB);
  bf16*  pwT_bf  = (bf16*)(ws + 200 * MB);
  bf16*  WB_bf   = (bf16*)(ws + 200 * MB);
  bf16*  hb_bf   = (bf16*)(ws + 208 * MB);
  bf16*  Fb_bf   = (bf16*)(ws + 208 * MB);
  bf16*  Ht_bf   = (bf16*)(ws + 212 * MB);
  bf16*  out_bf  = (bf16*)(ws + 216 * MB);
  float* T1      = (float*)(ws + 220 * MB);
  float* cvec    = (float*)(ws + 220 * MB + 64 * KB);
  float* b_H     = (float*)(ws + 220 * MB + 68 * KB);
  float* bias_z  = (float*)(ws + 220 * MB + 72 * KB);
  bf16*  Wp      = (bf16*)(ws + 220 * MB + 80 * KB);
  float* T2t     = (float*)(ws + 220 * MB + 592 * KB);

  // ---- weight prep ----
  prep_cvt_kernel<<<8192, 256, 0, stream>>>(in_w, hb_w, out_w, in_wbf, hb_bf, out_bf);
  transpose_kernel<<<dim3(64, 64), 256, 0, stream>>>(pw_w, pwT_bf);
  gemm_bt<EPI_PLAIN><<<dim3(8, 16), 256, 0, stream>>>(
      pwT_bf, hb_bf, nullptr, Ht_bf, nullptr, nullptr, nullptr, nullptr, 1024, 2048, 1024, 0);
  prep_small_kernel<<<3085, 256, 0, stream>>>(
      Bm, ha_w, dwa_b, dwa_k, Amat, hb_w, pw_b, hb_b, fuse_w,
      T1, cvec, b_H, Wp, Fb_bf);
  gemm_bt<EPI_PLAIN><<<dim3(16, 16), 256, 0, stream>>>(
      Fb_bf, Ht_bf, nullptr, WB_bf, nullptr, nullptr, nullptr, nullptr, 2048, 1024, 2048, 0);
  prep_fuse_kernel<<<136, 256, 0, stream>>>(T1, fuse_w, fuse_b, ha_b, b_H, T2t, bias_z);

  // ---- main chain ----
  rmsnorm_kernel<<<MTOK, 256, 0, stream>>>(x, norm_w, hnorm);
  // in-proj (256^2): gate = sigmoid(h[:, :DI]), val = h[:, DI:]
  gemm256<EPI_SPLIT><<<dim3(16, 64), 512, 0, stream>>>(
      hnorm, in_wbf, in_b, gatep, valp, nullptr, nullptr, nullptr, 1024, DI);
  conv_kernel<<<dim3(SEQ / TL2, 2, BATCH), 256, 0, stream>>>(
      valp, sym_k, sym_b, bsilu);
  gemm_bt<EPI_PLAIN, true><<<dim3(2, 128), 256, 0, stream>>>(
      valp, Wp, nullptr, Pbuf, nullptr, nullptr, nullptr, nullptr, 128, 2048, 128, 0);
  za_kernel<<<MTOK / 32, 256, 0, stream>>>(
      Pbuf, Pbuf + (size_t)MTOK * 128, T2t, cvec, bias_z, zbuf);
  // B-GEMM (256^2): y2 = gate * (bsilu @ W_B^T + z_a)  [in-place]
  gemm256<EPI_GATEADD><<<dim3(8, 64), 512, 0, stream>>>(
      bsilu, WB_bf, nullptr, zbuf, nullptr, gatep, nullptr, nullptr, 2048, 2048);
  // out GEMM (256^2) + residual -> fp32 d_out
  gemm256<EPI_RES><<<dim3(4, 64), 512, 0, stream>>>(
      zbuf, out_bf, out_b, nullptr, nullptr, nullptr, out, x, 2048, 1024);
}

// Round 4
// 920.071 us; speedup vs baseline: 1.1093x; 1.0179x over previous
//
#include <hip/hip_runtime.h>
#include <hip/hip_bf16.h>
#include <stdint.h>

typedef __bf16 bf16;
typedef __bf16 bf16x8 __attribute__((ext_vector_type(8)));
typedef __bf16 bf16x4 __attribute__((ext_vector_type(4)));
typedef float  f32x4  __attribute__((ext_vector_type(4)));

#define LDS_PTR(p) ((__attribute__((address_space(3))) uint32_t*)(p))
#define GLB_PTR(p) ((const __attribute__((address_space(1))) uint32_t*)(p))

static constexpr int BATCH = 4, SEQ = 4096, DMODEL = 1024;
static constexpr int DI = 2048;
static constexpr int MTOK = BATCH * SEQ;   // 16384 tokens

enum { EPI_SPLIT = 0, EPI_PLAIN = 1, EPI_GATEADD = 2, EPI_RES = 3 };

// ---------------------------------------------------------------------------
// 128x128-tile bf16 GEMM (m97 structure) — proven 175us on the big GEMMs;
// used for in-proj, out-GEMM, prep GEMMs, and the skinny split-K P GEMM.
// ---------------------------------------------------------------------------
template <int EPI, bool SPLITK = false>
__global__ __launch_bounds__(256) void gemm_bt(
    const bf16* __restrict__ Aact, const bf16* __restrict__ W,
    const float* __restrict__ bias,
    bf16* __restrict__ out0, bf16* __restrict__ out1,
    const bf16* __restrict__ gate,
    float* __restrict__ outf, const float* __restrict__ resid,
    int N, int K, int ldC, int col_off)
{
  __shared__ __align__(16) bf16 sA[128 * 64];
  __shared__ __align__(16) bf16 sB[128 * 64];
  const int tid  = threadIdx.x;
  int n0, m0, kbeg, kend;
  size_t out_off = 0;
  if (SPLITK) {
    n0 = 0; m0 = blockIdx.y * 128;
    const int kh = K / gridDim.x;
    kbeg = blockIdx.x * kh; kend = kbeg + kh;
    out_off = (size_t)blockIdx.x * ((size_t)MTOK * 128);
  } else {
    const int nT  = gridDim.x;
    const int lin = blockIdx.y * nT + blockIdx.x;
    const int grp = lin / (8 * nT);
    const int within = lin - grp * (8 * nT);
    n0 = (within >> 3) * 128;
    m0 = (grp * 8 + (within & 7)) * 128;
    kbeg = 0; kend = K;
  }
  const int lane = tid & 63;
  const int wv   = tid >> 6;
  const int wr   = wv >> 1, wc = wv & 1;
  const int l15  = lane & 15, quad = lane >> 4;

  f32x4 acc[4][4];
#pragma unroll
  for (int i = 0; i < 4; ++i)
#pragma unroll
    for (int j = 0; j < 4; ++j) acc[i][j] = (f32x4){0.f, 0.f, 0.f, 0.f};

  int rr[4], cb[4];
#pragma unroll
  for (int j = 0; j < 4; ++j) {
    const int s = tid + j * 256;
    rr[j] = s >> 3;
    cb[j] = ((s & 7) ^ (rr[j] & 7)) * 16;
  }

  const char* gA = (const char*)(Aact + (size_t)m0 * K);
  const char* gW = (const char*)(W + (size_t)n0 * K);

  for (int k0 = kbeg; k0 < kend; k0 += 64) {
    if (k0 != kbeg) __syncthreads();
#pragma unroll
    for (int j = 0; j < 4; ++j)
      __builtin_amdgcn_global_load_lds(GLB_PTR(gA + ((size_t)rr[j] * K + k0) * 2 + cb[j]),
                                       LDS_PTR(sA + (tid + j * 256) * 8), 16, 0, 0);
#pragma unroll
    for (int j = 0; j < 4; ++j)
      __builtin_amdgcn_global_load_lds(GLB_PTR(gW + ((size_t)rr[j] * K + k0) * 2 + cb[j]),
                                       LDS_PTR(sB + (tid + j * 256) * 8), 16, 0, 0);
    __syncthreads();

#pragma unroll
    for (int h = 0; h < 2; ++h) {
      bf16x8 av[4], bv[4];
#pragma unroll
      for (int t = 0; t < 4; ++t) {
        const int Ra = wr * 64 + t * 16 + l15;
        const int Rb = wc * 64 + t * 16 + l15;
        const int cc = h * 4 + quad;
        av[t] = *(const bf16x8*)(sA + (Ra * 8 + (cc ^ (Ra & 7))) * 8);
        bv[t] = *(const bf16x8*)(sB + (Rb * 8 + (cc ^ (Rb & 7))) * 8);
      }
#pragma unroll
      for (int i = 0; i < 4; ++i)
#pragma unroll
        for (int j = 0; j < 4; ++j)
          acc[i][j] = __builtin_amdgcn_mfma_f32_16x16x32_bf16(av[i], bv[j], acc[i][j], 0, 0, 0);
    }
  }

  bf16* o0 = out0 + out_off;
#pragma unroll
  for (int i = 0; i < 4; ++i) {
    const int mbase = m0 + wr * 64 + i * 16 + quad * 4;
#pragma unroll
    for (int j = 0; j < 4; ++j) {
      const int n = n0 + wc * 64 + j * 16 + l15;
      const float bj = bias ? bias[n] : 0.f;
#pragma unroll
      for (int r = 0; r < 4; ++r) {
        const int mm = mbase + r;
        float v = acc[i][j][r] + bj;
        if (EPI == EPI_SPLIT) {
          if (n < DI) o0[(size_t)mm * DI + n] = (bf16)(1.f / (1.f + __expf(-v)));
          else        out1[(size_t)mm * DI + (n - DI)] = (bf16)v;
        } else if (EPI == EPI_PLAIN) {
          o0[(size_t)mm * ldC + col_off + n] = (bf16)v;
        } else if (EPI == EPI_GATEADD) {
          const size_t idx = (size_t)mm * ldC + n;
          float zz = (float)o0[idx];
          float g  = (float)gate[(size_t)mm * DI + n];
          o0[idx] = (bf16)((v + zz) * g);
        } else {
          outf[(size_t)mm * ldC + n] = v + resid[(size_t)mm * ldC + n];
        }
      }
    }
  }
}

// ---------------------------------------------------------------------------
// 256x256-tile, 8-wave bf16 GEMM v3 — minimal-barrier slip schedule.
// Per-wave output 128x64 (2M x 4N warps); 4 accumulator-quadrant phases per
// K-tile (BK=64): (qm0,qn0) (qm0,qn1) (qm1,qn1) (qm1,qn0), ds_read_b128
// per tile 12/4/8/0. Cross-phase operands live in registers.
// ONLY TWO barriers per K-tile (liveness-audited):
//   end-ph3: all waves done reading cur.h0 (ph1) / cur.*h1 (ph2,ph3)
//            -> ph4 may DMA-overwrite cur.h0, next ph1 may overwrite cur.h1
//   mid-ph4: after per-wave vmcnt(4) -> publishes tile t+1's DMA writes.
// All other waits are PER-WAVE lgkmcnt(0) before each MFMA cluster, so waves
// slip: one wave's ds_read burst overlaps another's MFMA (setprio arbitration
// has a role-split to exploit). vmcnt FIFO per wave: kept-4 [h0(t+1)] +
// ph1's 4 [h1(t+1)] + ph4's 4 [h0(t+2)] = 12; vmcnt(4) retires all of tile
// t+1, retains h0(t+2). Tail stages wrap to k=0/64 (dead but valid).
// ---------------------------------------------------------------------------
#define G256_STAGE(gmat, smat, dstoff, half, k0)                                  \
  do {                                                                            \
    const char* _g = (gmat) + ((size_t)((half) * 128 + r0) * K + (size_t)(k0)) * 2 + c0; \
    const int _d = (dstoff) + (half) * 8192 + tid * 8;                            \
    __builtin_amdgcn_global_load_lds(GLB_PTR(_g), LDS_PTR((smat) + _d), 16, 0, 0); \
    __builtin_amdgcn_global_load_lds(GLB_PTR(_g + (size_t)128 * K),               \
                                     LDS_PTR((smat) + _d + 4096), 16, 0, 0);      \
  } while (0)

#define RD_A(dst, ROWBASE)                                                        \
  _Pragma("unroll")                                                               \
  for (int kk = 0; kk < 2; ++kk) {                                                \
    _Pragma("unroll")                                                             \
    for (int i = 0; i < 4; ++i) {                                                 \
      const int R = (ROWBASE) + i * 16 + l15;                                     \
      const int cc = kk * 4 + quad;                                               \
      dst[kk][i] = *(const bf16x8*)(sA + cur + (R >> 7) * 8192 +                  \
                                    ((R & 127) * 8 + (cc ^ (R & 7))) * 8);        \
    }                                                                             \
  }

#define RD_B(dst, ROWBASE)                                                        \
  _Pragma("unroll")                                                               \
  for (int kk = 0; kk < 2; ++kk) {                                                \
    _Pragma("unroll")                                                             \
    for (int j = 0; j < 2; ++j) {                                                 \
      const int R = (ROWBASE) + j * 16 + l15;                                     \
      const int cc = kk * 4 + quad;                                               \
      dst[kk][j] = *(const bf16x8*)(sB + cur + (R >> 7) * 8192 +                  \
                                    ((R & 127) * 8 + (cc ^ (R & 7))) * 8);        \
    }                                                                             \
  }

#define LGKM0_SGB                                                                 \
  asm volatile("s_waitcnt lgkmcnt(0)" ::: "memory");                              \
  __builtin_amdgcn_sched_barrier(0);

#define MF16(AV, BV, I0, J0)                                                      \
  __builtin_amdgcn_s_setprio(1);                                                  \
  _Pragma("unroll")                                                               \
  for (int kk = 0; kk < 2; ++kk)                                                  \
    _Pragma("unroll")                                                             \
    for (int i = 0; i < 4; ++i)                                                   \
      _Pragma("unroll")                                                           \
      for (int j = 0; j < 2; ++j)                                                 \
        acc[(I0) + i][(J0) + j] = __builtin_amdgcn_mfma_f32_16x16x32_bf16(        \
            AV[kk][i], BV[kk][j], acc[(I0) + i][(J0) + j], 0, 0, 0);              \
  __builtin_amdgcn_s_setprio(0);

template <int EPI>
__global__ __launch_bounds__(512, 2) void gemm256(
    const bf16* __restrict__ Aact, const bf16* __restrict__ W,
    const float* __restrict__ bias,
    bf16* __restrict__ out0, bf16* __restrict__ out1,
    const bf16* __restrict__ gate,
    float* __restrict__ outf, const float* __restrict__ resid,
    int K, int ldC)
{
  __shared__ __align__(16) bf16 sA[2 * 16384];   // 2 buf x 256 rows x 64 k
  __shared__ __align__(16) bf16 sB[2 * 16384];
  const int tid = threadIdx.x;

  // GM=8 m-group swizzle: same-XCD consecutive blocks share the A-panel
  const int nT  = gridDim.x;
  const int lin = blockIdx.y * nT + blockIdx.x;
  const int grp = lin / (8 * nT);
  const int within = lin - grp * (8 * nT);
  const int n0 = (within >> 3) * 256;
  const int m0 = (grp * 8 + (within & 7)) * 256;

  const int lane = tid & 63;
  const int wv   = tid >> 6;        // 0..7
  const int wr   = wv >> 2;         // 0..1 : 128-row slice
  const int wc   = wv & 3;          // 0..3 : 64-col slice
  const int l15  = lane & 15, quad = lane >> 4;

  f32x4 acc[8][4];
#pragma unroll
  for (int i = 0; i < 8; ++i)
#pragma unroll
    for (int j = 0; j < 4; ++j) acc[i][j] = (f32x4){0.f, 0.f, 0.f, 0.f};

  // staging geometry: 1024 16B chunks per half-tile, 2 per thread
  const int r0 = tid >> 3;
  const int c0 = ((tid & 7) ^ (r0 & 7)) * 16;   // (r0+64)&7 == r0&7

  const char* gA = (const char*)(Aact + (size_t)m0 * K);
  const char* gW = (const char*)(W + (size_t)n0 * K);

  const int NT = K >> 6;

  // prologue: tile0 (4 half-tiles) + tile1 h0 pair; retain tile1.h0 (4 loads)
  G256_STAGE(gA, sA, 0, 0, 0);
  G256_STAGE(gW, sB, 0, 0, 0);
  G256_STAGE(gA, sA, 0, 1, 0);
  G256_STAGE(gW, sB, 0, 1, 0);
  G256_STAGE(gA, sA, 16384, 0, 64);
  G256_STAGE(gW, sB, 16384, 0, 64);
  asm volatile("s_waitcnt vmcnt(4)" ::: "memory");
  __builtin_amdgcn_s_barrier();
  __builtin_amdgcn_sched_barrier(0);

  int cur = 0;
  for (int t = 0; t < NT; ++t) {
    const int kn1 = (t + 1 < NT ? t + 1 : 0) * 64;
    const int kn2 = (t + 2 < NT ? t + 2 : t + 2 - NT) * 64;
    const int nxt = cur ^ 16384;
    bf16x8 av0[2][4], av1[2][4], bv0[2][2], bv1[2][2];

    // ph1: (qm0,qn0) — read av0+bv0 (12), stage t+1 h1 pair -> nxt
    RD_A(av0, wr * 128);
    RD_B(bv0, wc * 64);
    G256_STAGE(gA, sA, nxt, 1, kn1);
    G256_STAGE(gW, sB, nxt, 1, kn1);
    LGKM0_SGB;
    MF16(av0, bv0, 0, 0);

    // ph2: (qm0,qn1) — read bv1 (4), reuse av0
    RD_B(bv1, wc * 64 + 32);
    LGKM0_SGB;
    MF16(av0, bv1, 0, 2);

    // ph3: (qm1,qn1) — read av1 (8), reuse bv1
    RD_A(av1, wr * 128 + 64);
    LGKM0_SGB;
    MF16(av1, bv1, 4, 2);

    // barrier A: all waves done reading cur.h0 (ph1) and cur.*.h1 (ph2/ph3)
    __builtin_amdgcn_s_barrier();
    __builtin_amdgcn_sched_barrier(0);

    // ph4: (qm1,qn0) — stage t+2 h0 pair -> cur, counted wait, publish
    G256_STAGE(gA, sA, cur, 0, kn2);
    G256_STAGE(gW, sB, cur, 0, kn2);
    asm volatile("s_waitcnt vmcnt(4)" ::: "memory");
    __builtin_amdgcn_s_barrier();          // barrier B: tile t+1 data visible
    __builtin_amdgcn_sched_barrier(0);
    MF16(av1, bv0, 4, 0);

    cur = nxt;
  }
  asm volatile("s_waitcnt vmcnt(0)" ::: "memory");

  // epilogue: C/D layout col = lane&15, row = quad*4 + r (m89-verified)
#pragma unroll
  for (int ifr = 0; ifr < 8; ++ifr) {
    const int mbase = m0 + wr * 128 + ifr * 16 + quad * 4;
#pragma unroll
    for (int jfr = 0; jfr < 4; ++jfr) {
      const int n = n0 + wc * 64 + jfr * 16 + l15;
      const float bj = bias ? bias[n] : 0.f;
#pragma unroll
      for (int r = 0; r < 4; ++r) {
        const int mm = mbase + r;
        float v = acc[ifr][jfr][r] + bj;
        if (EPI == EPI_SPLIT) {
          if (n < DI) out0[(size_t)mm * DI + n] = (bf16)(1.f / (1.f + __expf(-v)));
          else        out1[(size_t)mm * DI + (n - DI)] = (bf16)v;
        } else if (EPI == EPI_GATEADD) {
          const size_t idx = (size_t)mm * ldC + n;
          float zz = (float)out0[idx];
          float g  = (float)gate[(size_t)mm * DI + n];
          out0[idx] = (bf16)((v + zz) * g);
        } else {  // EPI_RES
          outf[(size_t)mm * ldC + n] = v + resid[(size_t)mm * ldC + n];
        }
      }
    }
  }
}

// ---------------------------------------------------------------------------
// RMSNorm: one block per token row (1024 fp32 -> 1024 bf16)
// ---------------------------------------------------------------------------
__global__ __launch_bounds__(256) void rmsnorm_kernel(
    const float* __restrict__ x, const float* __restrict__ w, bf16* __restrict__ out)
{
  const int row = blockIdx.x;
  const int tid = threadIdx.x;
  const float4 xv = ((const float4*)(x + (size_t)row * DMODEL))[tid];
  float s = xv.x * xv.x + xv.y * xv.y + xv.z * xv.z + xv.w * xv.w;
#pragma unroll
  for (int o = 32; o; o >>= 1) s += __shfl_xor(s, o);
  __shared__ float red[4];
  if ((tid & 63) == 0) red[tid >> 6] = s;
  __syncthreads();
  const float tot = red[0] + red[1] + red[2] + red[3];
  const float scale = rsqrtf(tot * (1.f / DMODEL) + 1e-6f);
  const float4 wv = ((const float4*)w)[tid];
  bf16x4 o4 = { (bf16)(xv.x * wv.x * scale), (bf16)(xv.y * wv.y * scale),
                (bf16)(xv.z * wv.z * scale), (bf16)(xv.w * wv.w * scale) };
  *(bf16x4*)(out + (size_t)row * DMODEL + tid * 4) = o4;
}

// ---------------------------------------------------------------------------
// 9-tap depthwise conv + silu, 4 channels/thread (bf16x4 loads).
// ---------------------------------------------------------------------------
static constexpr int TL2 = 64;
__global__ __launch_bounds__(256) void conv_kernel(
    const bf16* __restrict__ val,
    const float* __restrict__ sym_k, const float* __restrict__ sym_b,
    bf16* __restrict__ bbuf)
{
  const int d  = (blockIdx.y * 256 + threadIdx.x) * 4;
  const int b  = blockIdx.z;
  const int l0 = blockIdx.x * TL2;
  float wk[9][4], bs[4];
#pragma unroll
  for (int j = 0; j < 4; ++j) {
    bs[j] = sym_b[d + j];
#pragma unroll
    for (int k = 0; k < 9; ++k) wk[k][j] = sym_k[(d + j) * 9 + k];
  }
  const bf16* base = val + (size_t)b * SEQ * DI + d;

  float win[9][4];
#pragma unroll
  for (int j = 0; j < 8; ++j) {
    const int xr = l0 + j - 4;
    if (xr >= 0 && xr < SEQ) {
      bf16x4 v = *(const bf16x4*)(base + (size_t)xr * DI);
#pragma unroll
      for (int c = 0; c < 4; ++c) win[j][c] = (float)v[c];
    } else {
#pragma unroll
      for (int c = 0; c < 4; ++c) win[j][c] = 0.f;
    }
  }
  for (int t = 0; t < TL2; ++t) {
    const int xf = l0 + t + 4;
    if (xf < SEQ) {
      bf16x4 v = *(const bf16x4*)(base + (size_t)xf * DI);
#pragma unroll
      for (int c = 0; c < 4; ++c) win[8][c] = (float)v[c];
    } else {
#pragma unroll
      for (int c = 0; c < 4; ++c) win[8][c] = 0.f;
    }
    float sb[4];
#pragma unroll
    for (int c = 0; c < 4; ++c) sb[c] = bs[c];
#pragma unroll
    for (int k = 0; k < 9; ++k)
#pragma unroll
      for (int c = 0; c < 4; ++c) sb[c] += win[k][c] * wk[k][c];
    bf16x4 o;
#pragma unroll
    for (int c = 0; c < 4; ++c) o[c] = (bf16)(sb[c] / (1.f + __expf(-sb[c])));
    *(bf16x4*)(bbuf + ((size_t)b * SEQ + l0 + t) * DI + d) = o;
#pragma unroll
    for (int k = 0; k < 8; ++k)
#pragma unroll
      for (int c = 0; c < 4; ++c) win[k][c] = win[k + 1][c];
  }
}

// ---------------------------------------------------------------------------
// prep_cvt: merged fp32->bf16 conversions (in_w, hb_w, out_w)
// ---------------------------------------------------------------------------
__global__ __launch_bounds__(256) void prep_cvt_kernel(
    const float* __restrict__ in_w, const float* __restrict__ hb_w,
    const float* __restrict__ out_w,
    bf16* __restrict__ in_wbf, bf16* __restrict__ hb_bf, bf16* __restrict__ out_bf)
{
  const int b = blockIdx.x;
  const float* src; bf16* dst; size_t i;
  if (b < 4096)      { src = in_w;  dst = in_wbf; i = (size_t)b * 256 + threadIdx.x; }
  else if (b < 6144) { src = hb_w;  dst = hb_bf;  i = (size_t)(b - 4096) * 256 + threadIdx.x; }
  else               { src = out_w; dst = out_bf; i = (size_t)(b - 6144) * 256 + threadIdx.x; }
  const float4 v = ((const float4*)src)[i];
  bf16x4 o4 = { (bf16)v.x, (bf16)v.y, (bf16)v.z, (bf16)v.w };
  *(bf16x4*)(dst + 4 * i) = o4;
}

// pwT_bf[d][c] = (bf16)pw_w[c][d]   (2048x2048 transpose via LDS)
__global__ __launch_bounds__(256) void transpose_kernel(
    const float* __restrict__ in, bf16* __restrict__ out)
{
  __shared__ float s[32][33];
  const int tid = threadIdx.x;
  const int r = tid >> 5, x = tid & 31;
  const int c0 = blockIdx.y * 32, d0 = blockIdx.x * 32;
#pragma unroll
  for (int rr = r; rr < 32; rr += 8)
    s[rr][x] = in[(size_t)(c0 + rr) * 2048 + d0 + x];
  __syncthreads();
#pragma unroll
  for (int rr = r; rr < 32; rr += 8)
    out[(size_t)(d0 + rr) * 2048 + c0 + x] = (bf16)s[x][rr];
}

// ---------------------------------------------------------------------------
// prep_small: t1 (1024) | cvec (1) | bh (4) | wprep (8) | fbcopy (2048)
// ---------------------------------------------------------------------------
__global__ __launch_bounds__(256) void prep_small_kernel(
    const float* __restrict__ Bm, const float* __restrict__ ha_w,
    const float* __restrict__ dwa_b, const float* __restrict__ dwa_k,
    const float* __restrict__ A,
    const float* __restrict__ hb_w, const float* __restrict__ pw_b,
    const float* __restrict__ hb_b, const float* __restrict__ fuse_w,
    float* __restrict__ T1, float* __restrict__ cvec, float* __restrict__ b_H,
    bf16* __restrict__ Wp, bf16* __restrict__ Fb)
{
  const int b = blockIdx.x, tid = threadIdx.x;
  __shared__ float red[4][16];
  if (b < 1024) {
    const int o = b;
    float acc[16];
#pragma unroll
    for (int s = 0; s < 16; ++s) acc[s] = 0.f;
    for (int d = tid; d < 2048; d += 256) {
      const float w = ha_w[(size_t)o * 2048 + d];
#pragma unroll
      for (int s = 0; s < 16; ++s) acc[s] += Bm[s * 2048 + d] * w;
    }
    const int lane = tid & 63, wv = tid >> 6;
#pragma unroll
    for (int s = 0; s < 16; ++s) {
      float v = acc[s];
#pragma unroll
      for (int off = 32; off; off >>= 1) v += __shfl_xor(v, off);
      if (lane == s) red[wv][s] = v;
    }
    __syncthreads();
    if (tid < 16)
      T1[tid * 1024 + o] = red[0][tid] + red[1][tid] + red[2][tid] + red[3][tid];
  } else if (b == 1024) {
    float acc[16];
#pragma unroll
    for (int s = 0; s < 16; ++s) acc[s] = 0.f;
    for (int d = tid; d < 2048; d += 256) {
      const float w = dwa_b[d];
#pragma unroll
      for (int s = 0; s < 16; ++s) acc[s] += w * A[d * 16 + s];
    }
    const int lane = tid & 63, wv = tid >> 6;
#pragma unroll
    for (int s = 0; s < 16; ++s) {
      float v = acc[s];
#pragma unroll
      for (int off = 32; off; off >>= 1) v += __shfl_xor(v, off);
      if (lane == s) red[wv][s] = v;
    }
    __syncthreads();
    if (tid < 16) cvec[tid] = red[0][tid] + red[1][tid] + red[2][tid] + red[3][tid];
  } else if (b < 1029) {
    const int o = (b - 1025) * 256 + tid;
    float acc = hb_b[o];
    const float* hr = hb_w + (size_t)o * 2048;
    for (int c = 0; c < 2048; c += 4) {
      float4 h = *(const float4*)(hr + c);
      float4 p = *(const float4*)(pw_b + c);
      acc += h.x * p.x + h.y * p.y + h.z * p.z + h.w * p.w;
    }
    b_H[o] = acc;
  } else if (b < 1037) {
    const int d = (b - 1029) * 256 + tid;
    float kk[4], av[16];
#pragma unroll
    for (int k = 0; k < 4; ++k) kk[k] = dwa_k[d * 4 + k];
#pragma unroll
    for (int s = 0; s < 16; ++s) av[s] = A[d * 16 + s];
#pragma unroll
    for (int k = 0; k < 4; ++k)
#pragma unroll
      for (int s = 0; s < 16; ++s)
        Wp[(size_t)(k * 16 + s) * 2048 + d] = (bf16)(kk[k] * av[s]);
    for (int n = 64; n < 128; ++n) Wp[(size_t)n * 2048 + d] = (bf16)0.f;
  } else {
    const int idx = (b - 1037) * 256 + tid;
    const int n = idx >> 8, o4 = idx & 255;
    float4 v = ((const float4*)(fuse_w + (size_t)n * 2048 + 1024))[o4];
    bf16x4 o = { (bf16)v.x, (bf16)v.y, (bf16)v.z, (bf16)v.w };
    *(bf16x4*)(Fb + (size_t)n * 1024 + o4 * 4) = o;
  }
}

// ---------------------------------------------------------------------------
// prep_fuse: t2t (128 blocks) | biasz (8 blocks). Needs T1 and b_H.
// ---------------------------------------------------------------------------
__global__ __launch_bounds__(256) void prep_fuse_kernel(
    const float* __restrict__ T1, const float* __restrict__ fuse_w,
    const float* __restrict__ fuse_b, const float* __restrict__ ha_b,
    const float* __restrict__ b_H,
    float* __restrict__ T2t, float* __restrict__ bias_z)
{
  const int b = blockIdx.x, tid = threadIdx.x;
  if (b < 128) {
    const int n = b * 16 + (tid >> 4);
    const int s = tid & 15;
    const float* fr = fuse_w + (size_t)n * 2048;
    const float* tr = T1 + s * 1024;
    float acc = 0.f;
    for (int o = 0; o < 1024; o += 4) {
      float4 f = *(const float4*)(fr + o);
      float4 t = *(const float4*)(tr + o);
      acc += f.x * t.x + f.y * t.y + f.z * t.z + f.w * t.w;
    }
    T2t[n * 16 + s] = acc;
  } else {
    const int n = (b - 128) * 256 + tid;
    float acc = fuse_b[n];
    const float* fr = fuse_w + (size_t)n * 2048;
    for (int o = 0; o < 1024; o += 4) {
      float4 fa = *(const float4*)(fr + o);
      float4 fb = *(const float4*)(fr + 1024 + o);
      float4 ha = *(const float4*)(ha_b + o);
      float4 bh = *(const float4*)(b_H + o);
      acc += fa.x * ha.x + fa.y * ha.y + fa.z * ha.z + fa.w * ha.w;
      acc += fb.x * bh.x + fb.y * bh.y + fb.z * bh.z + fb.w * bh.w;
    }
    bias_z[n] = acc;
  }
}

// ---------------------------------------------------------------------------
// z_a[m,n] = bias_z[n] + sum_s s16[m,s]*T2t[n,s]; s16 from split-K P partials.
// ---------------------------------------------------------------------------
__global__ __launch_bounds__(256) void za_kernel(
    const bf16* __restrict__ P0, const bf16* __restrict__ P1,
    const float* __restrict__ T2t,
    const float* __restrict__ cvec, const float* __restrict__ bias_z,
    bf16* __restrict__ z)
{
  __shared__ float s16t[32][16];
  const int tid = threadIdx.x;
  const int tok0 = blockIdx.x * 32;
  for (int p = tid; p < 512; p += 256) {
    const int t = p >> 4, s = p & 15;
    const int tok = tok0 + t;
    const int l = tok & (SEQ - 1), bb = tok >> 12;
    float acc = cvec[s];
#pragma unroll
    for (int k = 0; k < 4; ++k) {
      const int r = l - 1 + k;
      if ((unsigned)r < (unsigned)SEQ) {
        const size_t idx = ((size_t)bb * SEQ + r) * 128 + k * 16 + s;
        acc += (float)P0[idx] + (float)P1[idx];
      }
    }
    s16t[t][s] = acc;
  }
  const int c0 = tid * 8;
  float t2[8][16], bz[8];
#pragma unroll
  for (int j = 0; j < 8; ++j) {
    bz[j] = bias_z[c0 + j];
#pragma unroll
    for (int q = 0; q < 4; ++q) {
      float4 v = ((const float4*)(T2t + (size_t)(c0 + j) * 16))[q];
      t2[j][q * 4 + 0] = v.x; t2[j][q * 4 + 1] = v.y;
      t2[j][q * 4 + 2] = v.z; t2[j][q * 4 + 3] = v.w;
    }
  }
  __syncthreads();
  for (int t = 0; t < 32; ++t) {
    float sv[16];
#pragma unroll
    for (int s = 0; s < 16; ++s) sv[s] = s16t[t][s];
    bf16x8 o;
#pragma unroll
    for (int j = 0; j < 8; ++j) {
      float a = bz[j];
#pragma unroll
      for (int s = 0; s < 16; ++s) a += sv[s] * t2[j][s];
      o[j] = (bf16)a;
    }
    *(bf16x8*)(z + (size_t)(tok0 + t) * 2048 + c0) = o;
  }
}

// ---------------------------------------------------------------------------
extern "C" void kernel_launch(void* const* d_in, const int* in_sizes, int n_in,
                              void* d_out, int out_size, void* d_ws, size_t ws_size,
                              hipStream_t stream)
{
  const float* x      = (const float*)d_in[0];
  const float* norm_w = (const float*)d_in[1];
  const float* in_w   = (const float*)d_in[2];
  const float* in_b   = (const float*)d_in[3];
  const float* dwa_k  = (const float*)d_in[4];
  const float* dwa_b  = (const float*)d_in[5];
  const float* Amat   = (const float*)d_in[6];
  const float* Bm     = (const float*)d_in[7];
  const float* sym_k  = (const float*)d_in[8];
  const float* sym_b  = (const float*)d_in[9];
  const float* pw_w   = (const float*)d_in[10];
  const float* pw_b   = (const float*)d_in[11];
  const float* ha_w   = (const float*)d_in[12];
  const float* ha_b   = (const float*)d_in[13];
  const float* hb_w   = (const float*)d_in[14];
  const float* hb_b   = (const float*)d_in[15];
  const float* fuse_w = (const float*)d_in[16];
  const float* fuse_b = (const float*)d_in[17];
  const float* out_w  = (const float*)d_in[18];
  const float* out_b  = (const float*)d_in[19];
  float* out = (float*)d_out;

  char* ws = (char*)d_ws;
  const size_t MB = 1u << 20, KB = 1u << 10;
  bf16*  in_wbf  = (bf16*)(ws + 0);
  bf16*  hnorm   = (bf16*)(ws + 8 * MB);
  bf16*  bsilu   = (bf16*)(ws + 0);
  bf16*  valp    = (bf16*)(ws + 64 * MB);
  bf16*  zbuf    = (bf16*)(ws + 64 * MB);
  bf16*  gatep   = (bf16*)(ws + 128 * MB);
  bf16*  Pbuf    = (bf16*)(ws + 192 * MB);
  bf16*  pwT_bf  = (bf16*)(ws + 200 * MB);
  bf16*  WB_bf   = (bf16*)(ws + 200 * MB);
  bf16*  hb_bf   = (bf16*)(ws + 208 * MB);
  bf16*  Fb_bf   = (bf16*)(ws + 208 * MB);
  bf16*  Ht_bf   = (bf16*)(ws + 212 * MB);
  bf16*  out_bf  = (bf16*)(ws + 216 * MB);
  float* T1      = (float*)(ws + 220 * MB);
  float* cvec    = (float*)(ws + 220 * MB + 64 * KB);
  float* b_H     = (float*)(ws + 220 * MB + 68 * KB);
  float* bias_z  = (float*)(ws + 220 * MB + 72 * KB);
  bf16*  Wp      = (bf16*)(ws + 220 * MB + 80 * KB);
  float* T2t     = (float*)(ws + 220 * MB + 592 * KB);

  // ---- weight prep ----
  prep_cvt_kernel<<<8192, 256, 0, stream>>>(in_w, hb_w, out_w, in_wbf, hb_bf, out_bf);
  transpose_kernel<<<dim3(64, 64), 256, 0, stream>>>(pw_w, pwT_bf);
  gemm_bt<EPI_PLAIN><<<dim3(8, 16), 256, 0, stream>>>(
      pwT_bf, hb_bf, nullptr, Ht_bf, nullptr, nullptr, nullptr, nullptr, 1024, 2048, 1024, 0);
  prep_small_kernel<<<3085, 256, 0, stream>>>(
      Bm, ha_w, dwa_b, dwa_k, Amat, hb_w, pw_b, hb_b, fuse_w,
      T1, cvec, b_H, Wp, Fb_bf);
  gemm_bt<EPI_PLAIN><<<dim3(16, 16), 256, 0, stream>>>(
      Fb_bf, Ht_bf, nullptr, WB_bf, nullptr, nullptr, nullptr, nullptr, 2048, 1024, 2048, 0);
  prep_fuse_kernel<<<136, 256, 0, stream>>>(T1, fuse_w, fuse_b, ha_b, b_H, T2t, bias_z);

  // ---- main chain ----
  rmsnorm_kernel<<<MTOK, 256, 0, stream>>>(x, norm_w, hnorm);
  // in-proj (proven gemm_bt): gate = sigmoid(h[:, :DI]), val = h[:, DI:]
  gemm_bt<EPI_SPLIT><<<dim3(32, 128), 256, 0, stream>>>(
      hnorm, in_wbf, in_b, gatep, valp, nullptr, nullptr, nullptr, 4096, 1024, DI, 0);
  conv_kernel<<<dim3(SEQ / TL2, 2, BATCH), 256, 0, stream>>>(
      valp, sym_k, sym_b, bsilu);
  gemm_bt<EPI_PLAIN, true><<<dim3(2, 128), 256, 0, stream>>>(
      valp, Wp, nullptr, Pbuf, nullptr, nullptr, nullptr, nullptr, 128, 2048, 128, 0);
  za_kernel<<<MTOK / 32, 256, 0, stream>>>(
      Pbuf, Pbuf + (size_t)MTOK * 128, T2t, cvec, bias_z, zbuf);
  // B-GEMM (256^2 v3 slip schedule): y2 = gate * (bsilu @ W_B^T + z_a)
  gemm256<EPI_GATEADD><<<dim3(8, 64), 512, 0, stream>>>(
      bsilu, WB_bf, nullptr, zbuf, nullptr, gatep, nullptr, nullptr, 2048, 2048);
  // out GEMM (proven gemm_bt) + residual -> fp32 d_out
  gemm_bt<EPI_RES><<<dim3(8, 128), 256, 0, stream>>>(
      zbuf, out_bf, out_b, nullptr, nullptr, nullptr, out, x, 1024, 2048, 1024, 0);
}

// Round 5
// 882.692 us; speedup vs baseline: 1.1562x; 1.0423x over previous
//
#include <hip/hip_runtime.h>
#include <hip/hip_bf16.h>
#include <stdint.h>

typedef __bf16 bf16;
typedef __bf16 bf16x8 __attribute__((ext_vector_type(8)));
typedef __bf16 bf16x4 __attribute__((ext_vector_type(4)));
typedef float  f32x4  __attribute__((ext_vector_type(4)));

#define LDS_PTR(p) ((__attribute__((address_space(3))) uint32_t*)(p))
#define GLB_PTR(p) ((const __attribute__((address_space(1))) uint32_t*)(p))

static constexpr int BATCH = 4, SEQ = 4096, DMODEL = 1024;
static constexpr int DI = 2048;
static constexpr int MTOK = BATCH * SEQ;   // 16384 tokens

enum { EPI_SPLIT = 0, EPI_PLAIN = 1, EPI_GATEADD = 2, EPI_RES = 3, EPI_F32S = 4 };

// ---------------------------------------------------------------------------
// 128x128-tile bf16 GEMM (m97 structure) — the proven workhorse (~780 TF).
// SPLITK: blockIdx.x = K-split, blockIdx.y = m-tile, blockIdx.z = n-tile.
//   EPI_PLAIN partials: bf16 at out0 + split*MTOK*128 (P-GEMM layout).
//   EPI_F32S  partials: fp32 at outf + split*col_off (Ht split-K).
// ---------------------------------------------------------------------------
template <int EPI, bool SPLITK = false>
__global__ __launch_bounds__(256) void gemm_bt(
    const bf16* __restrict__ Aact, const bf16* __restrict__ W,
    const float* __restrict__ bias,
    bf16* __restrict__ out0, bf16* __restrict__ out1,
    const bf16* __restrict__ gate,
    float* __restrict__ outf, const float* __restrict__ resid,
    int N, int K, int ldC, int col_off)
{
  __shared__ __align__(16) bf16 sA[128 * 64];
  __shared__ __align__(16) bf16 sB[128 * 64];
  const int tid  = threadIdx.x;
  int n0, m0, kbeg, kend;
  size_t out_off = 0;
  if (SPLITK) {
    n0 = blockIdx.z * 128;
    m0 = blockIdx.y * 128;
    const int kh = K / gridDim.x;
    kbeg = blockIdx.x * kh; kend = kbeg + kh;
    out_off = (EPI == EPI_F32S) ? (size_t)blockIdx.x * (size_t)col_off
                                : (size_t)blockIdx.x * ((size_t)MTOK * 128);
  } else {
    const int nT  = gridDim.x;
    const int lin = blockIdx.y * nT + blockIdx.x;
    const int grp = lin / (8 * nT);
    const int within = lin - grp * (8 * nT);
    n0 = (within >> 3) * 128;
    m0 = (grp * 8 + (within & 7)) * 128;
    kbeg = 0; kend = K;
  }
  const int lane = tid & 63;
  const int wv   = tid >> 6;
  const int wr   = wv >> 1, wc = wv & 1;
  const int l15  = lane & 15, quad = lane >> 4;

  f32x4 acc[4][4];
#pragma unroll
  for (int i = 0; i < 4; ++i)
#pragma unroll
    for (int j = 0; j < 4; ++j) acc[i][j] = (f32x4){0.f, 0.f, 0.f, 0.f};

  int rr[4], cb[4];
#pragma unroll
  for (int j = 0; j < 4; ++j) {
    const int s = tid + j * 256;
    rr[j] = s >> 3;
    cb[j] = ((s & 7) ^ (rr[j] & 7)) * 16;
  }

  const char* gA = (const char*)(Aact + (size_t)m0 * K);
  const char* gW = (const char*)(W + (size_t)n0 * K);

  for (int k0 = kbeg; k0 < kend; k0 += 64) {
    if (k0 != kbeg) __syncthreads();
#pragma unroll
    for (int j = 0; j < 4; ++j)
      __builtin_amdgcn_global_load_lds(GLB_PTR(gA + ((size_t)rr[j] * K + k0) * 2 + cb[j]),
                                       LDS_PTR(sA + (tid + j * 256) * 8), 16, 0, 0);
#pragma unroll
    for (int j = 0; j < 4; ++j)
      __builtin_amdgcn_global_load_lds(GLB_PTR(gW + ((size_t)rr[j] * K + k0) * 2 + cb[j]),
                                       LDS_PTR(sB + (tid + j * 256) * 8), 16, 0, 0);
    __syncthreads();

#pragma unroll
    for (int h = 0; h < 2; ++h) {
      bf16x8 av[4], bv[4];
#pragma unroll
      for (int t = 0; t < 4; ++t) {
        const int Ra = wr * 64 + t * 16 + l15;
        const int Rb = wc * 64 + t * 16 + l15;
        const int cc = h * 4 + quad;
        av[t] = *(const bf16x8*)(sA + (Ra * 8 + (cc ^ (Ra & 7))) * 8);
        bv[t] = *(const bf16x8*)(sB + (Rb * 8 + (cc ^ (Rb & 7))) * 8);
      }
#pragma unroll
      for (int i = 0; i < 4; ++i)
#pragma unroll
        for (int j = 0; j < 4; ++j)
          acc[i][j] = __builtin_amdgcn_mfma_f32_16x16x32_bf16(av[i], bv[j], acc[i][j], 0, 0, 0);
    }
  }

  bf16*  o0 = out0 + out_off;
  float* of = outf ? outf + out_off : nullptr;
  // epilogue: C/D layout col = lane&15, row = quad*4 + r (m89-verified)
#pragma unroll
  for (int i = 0; i < 4; ++i) {
    const int mbase = m0 + wr * 64 + i * 16 + quad * 4;
#pragma unroll
    for (int j = 0; j < 4; ++j) {
      const int n = n0 + wc * 64 + j * 16 + l15;
      const float bj = bias ? bias[n] : 0.f;
#pragma unroll
      for (int r = 0; r < 4; ++r) {
        const int mm = mbase + r;
        float v = acc[i][j][r] + bj;
        if (EPI == EPI_SPLIT) {
          if (n < DI) o0[(size_t)mm * DI + n] = (bf16)(1.f / (1.f + __expf(-v)));
          else        out1[(size_t)mm * DI + (n - DI)] = (bf16)v;
        } else if (EPI == EPI_PLAIN) {
          o0[(size_t)mm * ldC + col_off + n] = (bf16)v;
        } else if (EPI == EPI_GATEADD) {
          const size_t idx = (size_t)mm * ldC + n;
          float zz = (float)o0[idx];
          float g  = (float)gate[(size_t)mm * DI + n];
          o0[idx] = (bf16)((v + zz) * g);
        } else if (EPI == EPI_F32S) {
          of[(size_t)mm * ldC + n] = v;
        } else {  // EPI_RES: fp32 out + residual
          outf[(size_t)mm * ldC + n] = v + resid[(size_t)mm * ldC + n];
        }
      }
    }
  }
}

// ---------------------------------------------------------------------------
// RMSNorm: one block per token row (1024 fp32 -> 1024 bf16)
// ---------------------------------------------------------------------------
__global__ __launch_bounds__(256) void rmsnorm_kernel(
    const float* __restrict__ x, const float* __restrict__ w, bf16* __restrict__ out)
{
  const int row = blockIdx.x;
  const int tid = threadIdx.x;
  const float4 xv = ((const float4*)(x + (size_t)row * DMODEL))[tid];
  float s = xv.x * xv.x + xv.y * xv.y + xv.z * xv.z + xv.w * xv.w;
#pragma unroll
  for (int o = 32; o; o >>= 1) s += __shfl_xor(s, o);
  __shared__ float red[4];
  if ((tid & 63) == 0) red[tid >> 6] = s;
  __syncthreads();
  const float tot = red[0] + red[1] + red[2] + red[3];
  const float scale = rsqrtf(tot * (1.f / DMODEL) + 1e-6f);
  const float4 wv = ((const float4*)w)[tid];
  bf16x4 o4 = { (bf16)(xv.x * wv.x * scale), (bf16)(xv.y * wv.y * scale),
                (bf16)(xv.z * wv.z * scale), (bf16)(xv.w * wv.w * scale) };
  *(bf16x4*)(out + (size_t)row * DMODEL + tid * 4) = o4;
}

// ---------------------------------------------------------------------------
// 9-tap depthwise conv + silu, 4 channels/thread (bf16x4 loads).
// TL2=32 (was 64): 1024 blocks = 4/CU for latency hiding.
// ---------------------------------------------------------------------------
static constexpr int TL2 = 32;
__global__ __launch_bounds__(256) void conv_kernel(
    const bf16* __restrict__ val,
    const float* __restrict__ sym_k, const float* __restrict__ sym_b,
    bf16* __restrict__ bbuf)
{
  const int d  = (blockIdx.y * 256 + threadIdx.x) * 4;
  const int b  = blockIdx.z;
  const int l0 = blockIdx.x * TL2;
  float wk[9][4], bs[4];
#pragma unroll
  for (int j = 0; j < 4; ++j) {
    bs[j] = sym_b[d + j];
#pragma unroll
    for (int k = 0; k < 9; ++k) wk[k][j] = sym_k[(d + j) * 9 + k];
  }
  const bf16* base = val + (size_t)b * SEQ * DI + d;

  float win[9][4];
#pragma unroll
  for (int j = 0; j < 8; ++j) {
    const int xr = l0 + j - 4;
    if (xr >= 0 && xr < SEQ) {
      bf16x4 v = *(const bf16x4*)(base + (size_t)xr * DI);
#pragma unroll
      for (int c = 0; c < 4; ++c) win[j][c] = (float)v[c];
    } else {
#pragma unroll
      for (int c = 0; c < 4; ++c) win[j][c] = 0.f;
    }
  }
  for (int t = 0; t < TL2; ++t) {
    const int xf = l0 + t + 4;
    if (xf < SEQ) {
      bf16x4 v = *(const bf16x4*)(base + (size_t)xf * DI);
#pragma unroll
      for (int c = 0; c < 4; ++c) win[8][c] = (float)v[c];
    } else {
#pragma unroll
      for (int c = 0; c < 4; ++c) win[8][c] = 0.f;
    }
    float sb[4];
#pragma unroll
    for (int c = 0; c < 4; ++c) sb[c] = bs[c];
#pragma unroll
    for (int k = 0; k < 9; ++k)
#pragma unroll
      for (int c = 0; c < 4; ++c) sb[c] += win[k][c] * wk[k][c];
    bf16x4 o;
#pragma unroll
    for (int c = 0; c < 4; ++c) o[c] = (bf16)(sb[c] / (1.f + __expf(-sb[c])));
    *(bf16x4*)(bbuf + ((size_t)b * SEQ + l0 + t) * DI + d) = o;
#pragma unroll
    for (int k = 0; k < 8; ++k)
#pragma unroll
      for (int c = 0; c < 4; ++c) win[k][c] = win[k + 1][c];
  }
}

// ---------------------------------------------------------------------------
// prep_cvt: merged fp32->bf16 conversions (in_w, hb_w, out_w)
// ---------------------------------------------------------------------------
__global__ __launch_bounds__(256) void prep_cvt_kernel(
    const float* __restrict__ in_w, const float* __restrict__ hb_w,
    const float* __restrict__ out_w,
    bf16* __restrict__ in_wbf, bf16* __restrict__ hb_bf, bf16* __restrict__ out_bf)
{
  const int b = blockIdx.x;
  const float* src; bf16* dst; size_t i;
  if (b < 4096)      { src = in_w;  dst = in_wbf; i = (size_t)b * 256 + threadIdx.x; }
  else if (b < 6144) { src = hb_w;  dst = hb_bf;  i = (size_t)(b - 4096) * 256 + threadIdx.x; }
  else               { src = out_w; dst = out_bf; i = (size_t)(b - 6144) * 256 + threadIdx.x; }
  const float4 v = ((const float4*)src)[i];
  bf16x4 o4 = { (bf16)v.x, (bf16)v.y, (bf16)v.z, (bf16)v.w };
  *(bf16x4*)(dst + 4 * i) = o4;
}

// pwT_bf[d][c] = (bf16)pw_w[c][d]   (2048x2048 transpose via LDS)
__global__ __launch_bounds__(256) void transpose_kernel(
    const float* __restrict__ in, bf16* __restrict__ out)
{
  __shared__ float s[32][33];
  const int tid = threadIdx.x;
  const int r = tid >> 5, x = tid & 31;
  const int c0 = blockIdx.y * 32, d0 = blockIdx.x * 32;
#pragma unroll
  for (int rr = r; rr < 32; rr += 8)
    s[rr][x] = in[(size_t)(c0 + rr) * 2048 + d0 + x];
  __syncthreads();
#pragma unroll
  for (int rr = r; rr < 32; rr += 8)
    out[(size_t)(d0 + rr) * 2048 + c0 + x] = (bf16)s[x][rr];
}

// ---------------------------------------------------------------------------
// prep_small: t1 (1024) | cvec (1) | bh (4) | wprep (8) | fbcopy (2048)
//           | Ht combine (2048): Ht_bf = bf16(Hp0 + Hp1)  -> grid 5133
// ---------------------------------------------------------------------------
__global__ __launch_bounds__(256) void prep_small_kernel(
    const float* __restrict__ Bm, const float* __restrict__ ha_w,
    const float* __restrict__ dwa_b, const float* __restrict__ dwa_k,
    const float* __restrict__ A,
    const float* __restrict__ hb_w, const float* __restrict__ pw_b,
    const float* __restrict__ hb_b, const float* __restrict__ fuse_w,
    const float* __restrict__ Hp,
    float* __restrict__ T1, float* __restrict__ cvec, float* __restrict__ b_H,
    bf16* __restrict__ Wp, bf16* __restrict__ Fb, bf16* __restrict__ Ht)
{
  const int b = blockIdx.x, tid = threadIdx.x;
  __shared__ float red[4][16];
  if (b < 1024) {
    const int o = b;
    float acc[16];
#pragma unroll
    for (int s = 0; s < 16; ++s) acc[s] = 0.f;
    for (int d = tid; d < 2048; d += 256) {
      const float w = ha_w[(size_t)o * 2048 + d];
#pragma unroll
      for (int s = 0; s < 16; ++s) acc[s] += Bm[s * 2048 + d] * w;
    }
    const int lane = tid & 63, wv = tid >> 6;
#pragma unroll
    for (int s = 0; s < 16; ++s) {
      float v = acc[s];
#pragma unroll
      for (int off = 32; off; off >>= 1) v += __shfl_xor(v, off);
      if (lane == s) red[wv][s] = v;
    }
    __syncthreads();
    if (tid < 16)
      T1[tid * 1024 + o] = red[0][tid] + red[1][tid] + red[2][tid] + red[3][tid];
  } else if (b == 1024) {
    float acc[16];
#pragma unroll
    for (int s = 0; s < 16; ++s) acc[s] = 0.f;
    for (int d = tid; d < 2048; d += 256) {
      const float w = dwa_b[d];
#pragma unroll
      for (int s = 0; s < 16; ++s) acc[s] += w * A[d * 16 + s];
    }
    const int lane = tid & 63, wv = tid >> 6;
#pragma unroll
    for (int s = 0; s < 16; ++s) {
      float v = acc[s];
#pragma unroll
      for (int off = 32; off; off >>= 1) v += __shfl_xor(v, off);
      if (lane == s) red[wv][s] = v;
    }
    __syncthreads();
    if (tid < 16) cvec[tid] = red[0][tid] + red[1][tid] + red[2][tid] + red[3][tid];
  } else if (b < 1029) {
    const int o = (b - 1025) * 256 + tid;
    float acc = hb_b[o];
    const float* hr = hb_w + (size_t)o * 2048;
    for (int c = 0; c < 2048; c += 4) {
      float4 h = *(const float4*)(hr + c);
      float4 p = *(const float4*)(pw_b + c);
      acc += h.x * p.x + h.y * p.y + h.z * p.z + h.w * p.w;
    }
    b_H[o] = acc;
  } else if (b < 1037) {
    const int d = (b - 1029) * 256 + tid;
    float kk[4], av[16];
#pragma unroll
    for (int k = 0; k < 4; ++k) kk[k] = dwa_k[d * 4 + k];
#pragma unroll
    for (int s = 0; s < 16; ++s) av[s] = A[d * 16 + s];
#pragma unroll
    for (int k = 0; k < 4; ++k)
#pragma unroll
      for (int s = 0; s < 16; ++s)
        Wp[(size_t)(k * 16 + s) * 2048 + d] = (bf16)(kk[k] * av[s]);
    for (int n = 64; n < 128; ++n) Wp[(size_t)n * 2048 + d] = (bf16)0.f;
  } else if (b < 3085) {
    const int idx = (b - 1037) * 256 + tid;
    const int n = idx >> 8, o4 = idx & 255;
    float4 v = ((const float4*)(fuse_w + (size_t)n * 2048 + 1024))[o4];
    bf16x4 o = { (bf16)v.x, (bf16)v.y, (bf16)v.z, (bf16)v.w };
    *(bf16x4*)(Fb + (size_t)n * 1024 + o4 * 4) = o;
  } else {
    // Ht split-K combine: 2048 blocks x 256 threads x 1 float4
    const size_t e4 = (size_t)(b - 3085) * 256 + tid;
    float4 p0 = ((const float4*)Hp)[e4];
    float4 p1 = ((const float4*)(Hp + 2048 * 1024))[e4];
    bf16x4 o = { (bf16)(p0.x + p1.x), (bf16)(p0.y + p1.y),
                 (bf16)(p0.z + p1.z), (bf16)(p0.w + p1.w) };
    *(bf16x4*)(Ht + e4 * 4) = o;
  }
}

// ---------------------------------------------------------------------------
// prep_fuse: t2t (128 blocks) | biasz (2048 blocks, one per n). Grid 2176.
// biasz was 8 blocks (3% GPU) streaming 24 MB -> dominant prep cost; now a
// 256-thread row-reduction per output element.
// ---------------------------------------------------------------------------
__global__ __launch_bounds__(256) void prep_fuse_kernel(
    const float* __restrict__ T1, const float* __restrict__ fuse_w,
    const float* __restrict__ fuse_b, const float* __restrict__ ha_b,
    const float* __restrict__ b_H,
    float* __restrict__ T2t, float* __restrict__ bias_z)
{
  const int b = blockIdx.x, tid = threadIdx.x;
  if (b < 128) {
    const int n = b * 16 + (tid >> 4);
    const int s = tid & 15;
    const float* fr = fuse_w + (size_t)n * 2048;
    const float* tr = T1 + s * 1024;
    float acc = 0.f;
    for (int o = 0; o < 1024; o += 4) {
      float4 f = *(const float4*)(fr + o);
      float4 t = *(const float4*)(tr + o);
      acc += f.x * t.x + f.y * t.y + f.z * t.z + f.w * t.w;
    }
    T2t[n * 16 + s] = acc;
  } else {
    // bias_z[n] = fuse_b[n] + sum_o ha_b[o]*F_a[n,o] + sum_o b_H[o]*F_b[n,o]
    const int n = b - 128;
    const float* fr = fuse_w + (size_t)n * 2048;
    const int o = tid * 4;
    float4 fa = *(const float4*)(fr + o);
    float4 fb = *(const float4*)(fr + 1024 + o);
    float4 ha = *(const float4*)(ha_b + o);
    float4 bh = *(const float4*)(b_H + o);
    float acc = fa.x * ha.x + fa.y * ha.y + fa.z * ha.z + fa.w * ha.w
              + fb.x * bh.x + fb.y * bh.y + fb.z * bh.z + fb.w * bh.w;
#pragma unroll
    for (int off = 32; off; off >>= 1) acc += __shfl_xor(acc, off);
    __shared__ float r4[4];
    if ((tid & 63) == 0) r4[tid >> 6] = acc;
    __syncthreads();
    if (tid == 0) bias_z[n] = fuse_b[n] + r4[0] + r4[1] + r4[2] + r4[3];
  }
}

// ---------------------------------------------------------------------------
// z_a[m,n] = bias_z[n] + sum_s s16[m,s]*T2t[n,s]; s16 from split-K P partials.
// ---------------------------------------------------------------------------
__global__ __launch_bounds__(256) void za_kernel(
    const bf16* __restrict__ P0, const bf16* __restrict__ P1,
    const float* __restrict__ T2t,
    const float* __restrict__ cvec, const float* __restrict__ bias_z,
    bf16* __restrict__ z)
{
  __shared__ float s16t[32][16];
  const int tid = threadIdx.x;
  const int tok0 = blockIdx.x * 32;
  for (int p = tid; p < 512; p += 256) {
    const int t = p >> 4, s = p & 15;
    const int tok = tok0 + t;
    const int l = tok & (SEQ - 1), bb = tok >> 12;
    float acc = cvec[s];
#pragma unroll
    for (int k = 0; k < 4; ++k) {
      const int r = l - 1 + k;
      if ((unsigned)r < (unsigned)SEQ) {
        const size_t idx = ((size_t)bb * SEQ + r) * 128 + k * 16 + s;
        acc += (float)P0[idx] + (float)P1[idx];
      }
    }
    s16t[t][s] = acc;
  }
  const int c0 = tid * 8;
  float t2[8][16], bz[8];
#pragma unroll
  for (int j = 0; j < 8; ++j) {
    bz[j] = bias_z[c0 + j];
#pragma unroll
    for (int q = 0; q < 4; ++q) {
      float4 v = ((const float4*)(T2t + (size_t)(c0 + j) * 16))[q];
      t2[j][q * 4 + 0] = v.x; t2[j][q * 4 + 1] = v.y;
      t2[j][q * 4 + 2] = v.z; t2[j][q * 4 + 3] = v.w;
    }
  }
  __syncthreads();
  for (int t = 0; t < 32; ++t) {
    float sv[16];
#pragma unroll
    for (int s = 0; s < 16; ++s) sv[s] = s16t[t][s];
    bf16x8 o;
#pragma unroll
    for (int j = 0; j < 8; ++j) {
      float a = bz[j];
#pragma unroll
      for (int s = 0; s < 16; ++s) a += sv[s] * t2[j][s];
      o[j] = (bf16)a;
    }
    *(bf16x8*)(z + (size_t)(tok0 + t) * 2048 + c0) = o;
  }
}

// ---------------------------------------------------------------------------
extern "C" void kernel_launch(void* const* d_in, const int* in_sizes, int n_in,
                              void* d_out, int out_size, void* d_ws, size_t ws_size,
                              hipStream_t stream)
{
  const float* x      = (const float*)d_in[0];
  const float* norm_w = (const float*)d_in[1];
  const float* in_w   = (const float*)d_in[2];
  const float* in_b   = (const float*)d_in[3];
  const float* dwa_k  = (const float*)d_in[4];
  const float* dwa_b  = (const float*)d_in[5];
  const float* Amat   = (const float*)d_in[6];
  const float* Bm     = (const float*)d_in[7];
  const float* sym_k  = (const float*)d_in[8];
  const float* sym_b  = (const float*)d_in[9];
  const float* pw_w   = (const float*)d_in[10];
  const float* pw_b   = (const float*)d_in[11];
  const float* ha_w   = (const float*)d_in[12];
  const float* ha_b   = (const float*)d_in[13];
  const float* hb_w   = (const float*)d_in[14];
  const float* hb_b   = (const float*)d_in[15];
  const float* fuse_w = (const float*)d_in[16];
  const float* fuse_b = (const float*)d_in[17];
  const float* out_w  = (const float*)d_in[18];
  const float* out_b  = (const float*)d_in[19];
  float* out = (float*)d_out;

  char* ws = (char*)d_ws;
  const size_t MB = 1u << 20, KB = 1u << 10;
  // Overlay plan (peak ~220.8 MB):
  //  R0 [0,64):   in_wbf[0,8) + hnorm[8,40)  ->  bsilu
  //  R1 [64,128): Hpart (prep, 16 MB)  ->  val  ->  z_a  ->  y2 (in-place)
  //  R2 [128,192): gate
  bf16*  in_wbf  = (bf16*)(ws + 0);
  bf16*  hnorm   = (bf16*)(ws + 8 * MB);
  bf16*  bsilu   = (bf16*)(ws + 0);
  float* Hpart   = (float*)(ws + 64 * MB);              // 16 MB, prep-only
  bf16*  valp    = (bf16*)(ws + 64 * MB);
  bf16*  zbuf    = (bf16*)(ws + 64 * MB);
  bf16*  gatep   = (bf16*)(ws + 128 * MB);
  bf16*  Pbuf    = (bf16*)(ws + 192 * MB);              // 8 MB (2 split-K parts)
  bf16*  pwT_bf  = (bf16*)(ws + 200 * MB);              // 8 MB (dead after Ht)
  bf16*  WB_bf   = (bf16*)(ws + 200 * MB);              // 8 MB (overlays pwT)
  bf16*  hb_bf   = (bf16*)(ws + 208 * MB);              // 4 MB (dead after Ht)
  bf16*  Fb_bf   = (bf16*)(ws + 208 * MB);              // 4 MB (written post-Ht)
  bf16*  Ht_bf   = (bf16*)(ws + 212 * MB);              // 4 MB
  bf16*  out_bf  = (bf16*)(ws + 216 * MB);              // 4 MB
  float* T1      = (float*)(ws + 220 * MB);             // 64 KB
  float* cvec    = (float*)(ws + 220 * MB + 64 * KB);   // 64 B (pad to 4K)
  float* b_H     = (float*)(ws + 220 * MB + 68 * KB);   // 4 KB
  float* bias_z  = (float*)(ws + 220 * MB + 72 * KB);   // 8 KB
  bf16*  Wp      = (bf16*)(ws + 220 * MB + 80 * KB);    // 512 KB
  float* T2t     = (float*)(ws + 220 * MB + 592 * KB);  // 128 KB -> 220.70 MB

  // ---- weight prep ----
  prep_cvt_kernel<<<8192, 256, 0, stream>>>(in_w, hb_w, out_w, in_wbf, hb_bf, out_bf);
  transpose_kernel<<<dim3(64, 64), 256, 0, stream>>>(pw_w, pwT_bf);
  // Ht[d,o] = sum_c pw_w[c,d]*hb_w[o,c] — split-K=2, fp32 partials -> Hpart
  gemm_bt<EPI_F32S, true><<<dim3(2, 16, 8), 256, 0, stream>>>(
      pwT_bf, hb_bf, nullptr, nullptr, nullptr, nullptr, Hpart, nullptr,
      1024, 2048, 1024, 2048 * 1024);
  prep_small_kernel<<<5133, 256, 0, stream>>>(
      Bm, ha_w, dwa_b, dwa_k, Amat, hb_w, pw_b, hb_b, fuse_w, Hpart,
      T1, cvec, b_H, Wp, Fb_bf, Ht_bf);
  // W_B[n,d] = sum_o F_b[n,o]*Ht[d,o]  (= F_b@hb_w@pw_w)
  gemm_bt<EPI_PLAIN><<<dim3(16, 16), 256, 0, stream>>>(
      Fb_bf, Ht_bf, nullptr, WB_bf, nullptr, nullptr, nullptr, nullptr, 2048, 1024, 2048, 0);
  prep_fuse_kernel<<<2176, 256, 0, stream>>>(T1, fuse_w, fuse_b, ha_b, b_H, T2t, bias_z);

  // ---- main chain ----
  rmsnorm_kernel<<<MTOK, 256, 0, stream>>>(x, norm_w, hnorm);
  // in-proj: gate = sigmoid(h[:, :DI]), val = h[:, DI:]
  gemm_bt<EPI_SPLIT><<<dim3(32, 128), 256, 0, stream>>>(
      hnorm, in_wbf, in_b, gatep, valp, nullptr, nullptr, nullptr, 4096, 1024, DI, 0);
  // 9-tap conv + silu (val -> bsilu, overlays dead in_wbf/hnorm)
  conv_kernel<<<dim3(SEQ / TL2, 2, BATCH), 256, 0, stream>>>(
      valp, sym_k, sym_b, bsilu);
  // skinny P GEMM, split-K=2: P = val @ Wp^T  (N=128 padded)
  gemm_bt<EPI_PLAIN, true><<<dim3(2, 128), 256, 0, stream>>>(
      valp, Wp, nullptr, Pbuf, nullptr, nullptr, nullptr, nullptr, 128, 2048, 128, 0);
  // z_a = s16 @ T2 + bias_z  (writes R1, val now dead)
  za_kernel<<<MTOK / 32, 256, 0, stream>>>(
      Pbuf, Pbuf + (size_t)MTOK * 128, T2t, cvec, bias_z, zbuf);
  // B-GEMM: y2 = gate * (bsilu @ W_B^T + z_a)   [in-place over zbuf]
  gemm_bt<EPI_GATEADD><<<dim3(16, 128), 256, 0, stream>>>(
      bsilu, WB_bf, nullptr, zbuf, nullptr, gatep, nullptr, nullptr, 2048, 2048, 2048, 0);
  // out GEMM + residual -> fp32 d_out
  gemm_bt<EPI_RES><<<dim3(8, 128), 256, 0, stream>>>(
      zbuf, out_bf, out_b, nullptr, nullptr, nullptr, out, x, 1024, 2048, 1024, 0);
}